// Round 1
// baseline (691.474 us; speedup 1.0000x reference)
//
#include <hip/hip_runtime.h>
#include <cstdint>
#include <cstddef>

#define NN 50000
#define NE 800000
#define HEADS 4
#define HC 128     // HEADS*HID
#define OUTC 32

// ---------------------------------------------------------------------------
// helpers
// ---------------------------------------------------------------------------
__device__ __forceinline__ float lrelu(float v) {
    return v > 0.f ? v : 0.2f * v;
}
__device__ __forceinline__ float4 max4(float4 a, float4 b) {
    return make_float4(fmaxf(a.x, b.x), fmaxf(a.y, b.y), fmaxf(a.z, b.z), fmaxf(a.w, b.w));
}

// ---------------------------------------------------------------------------
// CSR build: zero counts -> count -> exclusive scan (single block) -> fill
// ---------------------------------------------------------------------------
__global__ void zero_kernel(int* __restrict__ p, int n) {
    int i = blockIdx.x * blockDim.x + threadIdx.x;
    if (i < n) p[i] = 0;
}

__global__ void count_kernel(const int* __restrict__ ei, int* __restrict__ cnt, int E) {
    int e = blockIdx.x * blockDim.x + threadIdx.x;
    if (e < E) {
        int d = ei[E + e];   // dst row
        atomicAdd(&cnt[d], 1);
    }
}

// single-block scan over n=50000 ints; also zeroes cnt for reuse as fill cursor
__global__ __launch_bounds__(1024) void scan_kernel(int* __restrict__ cnt,
                                                    int* __restrict__ off, int n) {
    __shared__ int wsum[16];
    __shared__ int carry_s;
    const int t = threadIdx.x;
    const int lane = t & 63, wid = t >> 6;
    if (t == 0) carry_s = 0;
    __syncthreads();
    for (int base = 0; base < n; base += 1024) {
        int i = base + t;
        int v = (i < n) ? cnt[i] : 0;
        if (i < n) cnt[i] = 0;
        // inclusive wave scan
        int x = v;
        #pragma unroll
        for (int o = 1; o < 64; o <<= 1) {
            int y = __shfl_up(x, o, 64);
            if (lane >= o) x += y;
        }
        if (lane == 63) wsum[wid] = x;
        __syncthreads();
        if (wid == 0) {
            int w = (lane < 16) ? wsum[lane] : 0;
            #pragma unroll
            for (int o = 1; o < 16; o <<= 1) {
                int y = __shfl_up(w, o, 64);
                if (lane >= o) w += y;
            }
            if (lane < 16) wsum[lane] = w;
        }
        __syncthreads();
        int wprefix = (wid > 0) ? wsum[wid - 1] : 0;
        int incl = x + wprefix;
        int carry = carry_s;
        if (i < n) off[i + 1] = carry + incl;
        int total = wsum[15];
        __syncthreads();
        if (t == 0) carry_s = carry + total;
        __syncthreads();
    }
    if (threadIdx.x == 0) off[0] = 0;
}

__global__ void fill_kernel(const int* __restrict__ ei, const int* __restrict__ off,
                            int* __restrict__ cursor, int* __restrict__ csr, int E) {
    int e = blockIdx.x * blockDim.x + threadIdx.x;
    if (e < E) {
        int s = ei[e];
        int d = ei[E + e];
        int pos = off[d] + atomicAdd(&cursor[d], 1);
        csr[pos] = s;
    }
}

// ---------------------------------------------------------------------------
// fp32 GEMM, K fixed at 128. A:[M,128] row-major, B:[128,N] row-major, C:[M,N]
// BM=64 BN=64 BK=32, 256 threads, 4x4 microtile
// ---------------------------------------------------------------------------
#define BM 64
#define BN 64
#define BKK 32
__global__ __launch_bounds__(256) void gemm_f32_k128(const float* __restrict__ A,
                                                     const float* __restrict__ B,
                                                     float* __restrict__ C,
                                                     int M, int N) {
    __shared__ float As[BM][BKK + 1];
    __shared__ float Bs[BKK][BN];
    const int tid = threadIdx.x;
    const int tx = tid & 15;
    const int ty = tid >> 4;
    const int m0 = blockIdx.x * BM;
    const int n0 = blockIdx.y * BN;

    float acc[4][4] = {};

    for (int k0 = 0; k0 < 128; k0 += BKK) {
        // A tile: 64 rows x 32 cols = 512 float4 loads
        #pragma unroll
        for (int L = tid; L < (BM * BKK) / 4; L += 256) {
            int r = L >> 3;            // 8 float4 per row
            int c4 = (L & 7) << 2;
            int row = m0 + r;
            float4 v = make_float4(0.f, 0.f, 0.f, 0.f);
            if (row < M)
                v = *reinterpret_cast<const float4*>(A + (size_t)row * 128 + k0 + c4);
            As[r][c4 + 0] = v.x; As[r][c4 + 1] = v.y;
            As[r][c4 + 2] = v.z; As[r][c4 + 3] = v.w;
        }
        // B tile: 32 rows x 64 cols
        #pragma unroll
        for (int L = tid; L < (BKK * BN) / 4; L += 256) {
            int r = L >> 4;            // 16 float4 per row
            int c4 = (L & 15) << 2;
            int col = n0 + c4;
            float4 v = make_float4(0.f, 0.f, 0.f, 0.f);
            if (col + 3 < N)
                v = *reinterpret_cast<const float4*>(B + (size_t)(k0 + r) * N + col);
            *reinterpret_cast<float4*>(&Bs[r][c4]) = v;
        }
        __syncthreads();
        #pragma unroll
        for (int kk = 0; kk < BKK; ++kk) {
            float a0 = As[ty * 4 + 0][kk];
            float a1 = As[ty * 4 + 1][kk];
            float a2 = As[ty * 4 + 2][kk];
            float a3 = As[ty * 4 + 3][kk];
            float4 b = *reinterpret_cast<const float4*>(&Bs[kk][tx * 4]);
            acc[0][0] += a0 * b.x; acc[0][1] += a0 * b.y; acc[0][2] += a0 * b.z; acc[0][3] += a0 * b.w;
            acc[1][0] += a1 * b.x; acc[1][1] += a1 * b.y; acc[1][2] += a1 * b.z; acc[1][3] += a1 * b.w;
            acc[2][0] += a2 * b.x; acc[2][1] += a2 * b.y; acc[2][2] += a2 * b.z; acc[2][3] += a2 * b.w;
            acc[3][0] += a3 * b.x; acc[3][1] += a3 * b.y; acc[3][2] += a3 * b.z; acc[3][3] += a3 * b.w;
        }
        __syncthreads();
    }

    #pragma unroll
    for (int i = 0; i < 4; ++i) {
        int row = m0 + ty * 4 + i;
        int col = n0 + tx * 4;
        if (row < M && col + 3 < N) {
            float4 v = make_float4(acc[i][0], acc[i][1], acc[i][2], acc[i][3]);
            *reinterpret_cast<float4*>(C + (size_t)row * N + col) = v;
        }
    }
}

// ---------------------------------------------------------------------------
// per-node attention logits: alS[n,h] = dot(hw[n,h,:], aS[h,:]), same for aD
// one block (128 thr) per node; reduce within 32-lane head groups
// ---------------------------------------------------------------------------
__global__ __launch_bounds__(128) void al_kernel(const float* __restrict__ hw,
                                                 const float* __restrict__ aS,
                                                 const float* __restrict__ aD,
                                                 float* __restrict__ alS,
                                                 float* __restrict__ alD) {
    const int n = blockIdx.x;
    const int t = threadIdx.x;
    float v = hw[(size_t)n * 128 + t];
    float ps = v * aS[t];
    float pd = v * aD[t];
    #pragma unroll
    for (int o = 16; o > 0; o >>= 1) {
        ps += __shfl_xor(ps, o, 32);
        pd += __shfl_xor(pd, o, 32);
    }
    if ((t & 31) == 0) {
        int h = t >> 5;
        alS[n * 4 + h] = ps;
        alD[n * 4 + h] = pd;
    }
}

// ---------------------------------------------------------------------------
// per-node softmax + aggregation + epilogue.
// FINAL=0: concat layers (out 128 wide, +b +bs +skip, ELU)
// FINAL=1: mean over heads, +b +bs +skip, L2 normalize, out 32 wide
// ---------------------------------------------------------------------------
template <int FINAL>
__global__ __launch_bounds__(128) void agg_kernel(const int* __restrict__ off,
                                                  const int* __restrict__ csr,
                                                  const float* __restrict__ alS,
                                                  const float* __restrict__ alD,
                                                  const float* __restrict__ hw,
                                                  const float* __restrict__ hsk,
                                                  const float* __restrict__ bias,
                                                  const float* __restrict__ biasSk,
                                                  float* __restrict__ out) {
    const int n = blockIdx.x;
    const int t = threadIdx.x;
    const int h = t >> 5;
    const int start = off[n];
    const int end = off[n + 1];

    const float4 ad4 = *reinterpret_cast<const float4*>(alD + (size_t)n * 4);

    // ---- pass 1: per-head max over incoming edges
    float4 mx = make_float4(-INFINITY, -INFINITY, -INFINITY, -INFINITY);
    for (int j = start + t; j < end; j += 128) {
        int s = csr[j];
        float4 as4 = *reinterpret_cast<const float4*>(alS + (size_t)s * 4);
        mx.x = fmaxf(mx.x, lrelu(as4.x + ad4.x));
        mx.y = fmaxf(mx.y, lrelu(as4.y + ad4.y));
        mx.z = fmaxf(mx.z, lrelu(as4.z + ad4.z));
        mx.w = fmaxf(mx.w, lrelu(as4.w + ad4.w));
    }
    __shared__ float4 red[128];
    __shared__ float mh4[4];
    red[t] = mx;
    __syncthreads();
    #pragma unroll
    for (int srd = 64; srd > 0; srd >>= 1) {
        if (t < srd) red[t] = max4(red[t], red[t + srd]);
        __syncthreads();
    }
    if (t < 4) mh4[t] = reinterpret_cast<const float*>(&red[0])[t];
    __syncthreads();
    const float m_h = mh4[h];
    const float ad_h = alD[(size_t)n * 4 + h];

    // ---- pass 2: exp-sum + weighted accumulate (serial over edges, unroll x2)
    float acc = 0.f, ssum = 0.f;
    int j = start;
    for (; j + 2 <= end; j += 2) {
        int s0 = csr[j], s1 = csr[j + 1];
        float als0 = alS[(size_t)s0 * 4 + h];
        float als1 = alS[(size_t)s1 * 4 + h];
        float hv0 = hw[(size_t)s0 * 128 + t];
        float hv1 = hw[(size_t)s1 * 128 + t];
        float x0 = __expf(lrelu(als0 + ad_h) - m_h);
        float x1 = __expf(lrelu(als1 + ad_h) - m_h);
        ssum += x0 + x1;
        acc += x0 * hv0 + x1 * hv1;
    }
    for (; j < end; ++j) {
        int s0 = csr[j];
        float als0 = alS[(size_t)s0 * 4 + h];
        float hv0 = hw[(size_t)s0 * 128 + t];
        float x0 = __expf(lrelu(als0 + ad_h) - m_h);
        ssum += x0;
        acc += x0 * hv0;
    }

    float gat = acc / (ssum + 1e-16f);

    if (FINAL == 0) {
        float val = gat + bias[t] + biasSk[t] + hsk[(size_t)n * 128 + t];
        val = val > 0.f ? val : expm1f(val);   // ELU
        out[(size_t)n * 128 + t] = val;
    } else {
        __shared__ float shv[128];
        shv[t] = gat;
        __syncthreads();
        if (t < 32) {
            float v = (shv[t] + shv[t + 32] + shv[t + 64] + shv[t + 96]) * 0.25f
                      + bias[t] + biasSk[t] + hsk[(size_t)n * 32 + t];
            float ss = v * v;
            #pragma unroll
            for (int o = 16; o > 0; o >>= 1) ss += __shfl_xor(ss, o, 32);
            float nrm = sqrtf(ss);
            out[(size_t)n * 32 + t] = v / fmaxf(nrm, 1e-12f);
        }
    }
}

// ---------------------------------------------------------------------------
// launch
// ---------------------------------------------------------------------------
extern "C" void kernel_launch(void* const* d_in, const int* in_sizes, int n_in,
                              void* d_out, int out_size, void* d_ws, size_t ws_size,
                              hipStream_t stream) {
    const float* x   = (const float*)d_in[0];
    const int*   ei  = (const int*)d_in[1];
    const float* W0  = (const float*)d_in[2];
    const float* aS0 = (const float*)d_in[3];
    const float* aD0 = (const float*)d_in[4];
    const float* b0  = (const float*)d_in[5];
    const float* Ws0 = (const float*)d_in[6];
    const float* bs0 = (const float*)d_in[7];
    const float* W1  = (const float*)d_in[8];
    const float* aS1 = (const float*)d_in[9];
    const float* aD1 = (const float*)d_in[10];
    const float* b1  = (const float*)d_in[11];
    const float* Ws1 = (const float*)d_in[12];
    const float* bs1 = (const float*)d_in[13];
    const float* W2  = (const float*)d_in[14];
    const float* aS2 = (const float*)d_in[15];
    const float* aD2 = (const float*)d_in[16];
    const float* b2  = (const float*)d_in[17];
    const float* Ws2 = (const float*)d_in[18];
    const float* bs2 = (const float*)d_in[19];
    float* out = (float*)d_out;

    char* p = (char*)d_ws;
    auto alloc = [&](size_t bytes) -> char* {
        char* q = p;
        p += (bytes + 255) & ~(size_t)255;
        return q;
    };
    int*   cnt  = (int*)alloc((size_t)NN * 4);
    int*   off  = (int*)alloc((size_t)(NN + 1) * 4);
    int*   csr  = (int*)alloc((size_t)NE * 4);
    float* hw   = (float*)alloc((size_t)NN * 128 * 4);
    float* hsk  = (float*)alloc((size_t)NN * 128 * 4);
    float* hbuf = (float*)alloc((size_t)NN * 128 * 4);
    float* alS  = (float*)alloc((size_t)NN * 4 * 4);
    float* alD  = (float*)alloc((size_t)NN * 4 * 4);

    const int EB = (NE + 255) / 256;
    const int MB = (NN + BM - 1) / BM;
    dim3 g128(MB, 2), g32(MB, 1);

    // CSR build (graph is identical for all 3 layers)
    zero_kernel<<<(NN + 255) / 256, 256, 0, stream>>>(cnt, NN);
    count_kernel<<<EB, 256, 0, stream>>>(ei, cnt, NE);
    scan_kernel<<<1, 1024, 0, stream>>>(cnt, off, NN);
    fill_kernel<<<EB, 256, 0, stream>>>(ei, off, cnt, csr, NE);

    // ---- layer 0 (in = x)
    gemm_f32_k128<<<g128, 256, 0, stream>>>(x, W0, hw, NN, 128);
    gemm_f32_k128<<<g128, 256, 0, stream>>>(x, Ws0, hsk, NN, 128);
    al_kernel<<<NN, 128, 0, stream>>>(hw, aS0, aD0, alS, alD);
    agg_kernel<0><<<NN, 128, 0, stream>>>(off, csr, alS, alD, hw, hsk, b0, bs0, hbuf);

    // ---- layer 1 (in = hbuf, out overwrites hbuf: safe, agg doesn't read it)
    gemm_f32_k128<<<g128, 256, 0, stream>>>(hbuf, W1, hw, NN, 128);
    gemm_f32_k128<<<g128, 256, 0, stream>>>(hbuf, Ws1, hsk, NN, 128);
    al_kernel<<<NN, 128, 0, stream>>>(hw, aS1, aD1, alS, alD);
    agg_kernel<0><<<NN, 128, 0, stream>>>(off, csr, alS, alD, hw, hsk, b1, bs1, hbuf);

    // ---- layer 2 (mean over heads, skip is [N,32], final normalize)
    gemm_f32_k128<<<g128, 256, 0, stream>>>(hbuf, W2, hw, NN, 128);
    gemm_f32_k128<<<g32, 256, 0, stream>>>(hbuf, Ws2, hsk, NN, 32);
    al_kernel<<<NN, 128, 0, stream>>>(hw, aS2, aD2, alS, alD);
    agg_kernel<1><<<NN, 128, 0, stream>>>(off, csr, alS, alD, hw, hsk, b2, bs2, out);
}

// Round 2
// 644.673 us; speedup vs baseline: 1.0726x; 1.0726x over previous
//
#include <hip/hip_runtime.h>
#include <cstdint>
#include <cstddef>

#define NN 50000
#define NE 800000

// ---------------------------------------------------------------------------
// helpers
// ---------------------------------------------------------------------------
__device__ __forceinline__ float lrelu(float v) {
    return v > 0.f ? v : 0.2f * v;
}

// ---------------------------------------------------------------------------
// CSR build: zero counts -> count -> exclusive scan (single block) -> fill
// ---------------------------------------------------------------------------
__global__ void zero_kernel(int* __restrict__ p, int n) {
    int i = blockIdx.x * blockDim.x + threadIdx.x;
    if (i < n) p[i] = 0;
}

__global__ void count_kernel(const int* __restrict__ ei, int* __restrict__ cnt, int E) {
    int e = blockIdx.x * blockDim.x + threadIdx.x;
    if (e < E) {
        int d = ei[E + e];   // dst row
        atomicAdd(&cnt[d], 1);
    }
}

// single-block scan over n=50000 ints; also zeroes cnt for reuse as fill cursor
__global__ __launch_bounds__(1024) void scan_kernel(int* __restrict__ cnt,
                                                    int* __restrict__ off, int n) {
    __shared__ int wsum[16];
    __shared__ int carry_s;
    const int t = threadIdx.x;
    const int lane = t & 63, wid = t >> 6;
    if (t == 0) carry_s = 0;
    __syncthreads();
    for (int base = 0; base < n; base += 1024) {
        int i = base + t;
        int v = (i < n) ? cnt[i] : 0;
        if (i < n) cnt[i] = 0;
        int x = v;
        #pragma unroll
        for (int o = 1; o < 64; o <<= 1) {
            int y = __shfl_up(x, o, 64);
            if (lane >= o) x += y;
        }
        if (lane == 63) wsum[wid] = x;
        __syncthreads();
        if (wid == 0) {
            int w = (lane < 16) ? wsum[lane] : 0;
            #pragma unroll
            for (int o = 1; o < 16; o <<= 1) {
                int y = __shfl_up(w, o, 64);
                if (lane >= o) w += y;
            }
            if (lane < 16) wsum[lane] = w;
        }
        __syncthreads();
        int wprefix = (wid > 0) ? wsum[wid - 1] : 0;
        int incl = x + wprefix;
        int carry = carry_s;
        if (i < n) off[i + 1] = carry + incl;
        int total = wsum[15];
        __syncthreads();
        if (t == 0) carry_s = carry + total;
        __syncthreads();
    }
    if (threadIdx.x == 0) off[0] = 0;
}

__global__ void fill_kernel(const int* __restrict__ ei, const int* __restrict__ off,
                            int* __restrict__ cursor, int* __restrict__ csr, int E) {
    int e = blockIdx.x * blockDim.x + threadIdx.x;
    if (e < E) {
        int s = ei[e];
        int d = ei[E + e];
        int pos = off[d] + atomicAdd(&cursor[d], 1);
        csr[pos] = s;
    }
}

// ---------------------------------------------------------------------------
// fused dual-B fp32 GEMM, K=128 fixed.
// A:[M,128] row-major. y==0: C1 = A@B1 (N=128). y==1: C2 = A@B2 (N=N2, 128 or 32).
// BM=128, BN=128, BK=32, 256 threads, 8x8 microtile (split 4+4 for bank-free LDS).
// ---------------------------------------------------------------------------
#define GBM 128
#define GBN 128
#define GBK 32
__global__ __launch_bounds__(256) void gemm_dual(const float* __restrict__ A,
                                                 const float* __restrict__ B1,
                                                 float* __restrict__ C1,
                                                 const float* __restrict__ B2,
                                                 float* __restrict__ C2,
                                                 int M, int N2) {
    __shared__ float As[GBK][GBM + 4];   // transposed A tile, pad 4 keeps 16B align
    __shared__ float Bs[GBK][GBN];
    const int tid = threadIdx.x;
    const int tx = tid & 15;
    const int ty = tid >> 4;
    const int m0 = blockIdx.x * GBM;
    const bool second = (blockIdx.y == 1);
    const float* __restrict__ B = second ? B2 : B1;
    float* __restrict__ C = second ? C2 : C1;
    const int Ncols = second ? N2 : 128;

    float acc[8][8];
    #pragma unroll
    for (int i = 0; i < 8; ++i)
        #pragma unroll
        for (int j = 0; j < 8; ++j) acc[i][j] = 0.f;

    for (int k0 = 0; k0 < 128; k0 += GBK) {
        // stage A: 128 rows x 32 k, transposed into As[k][row]
        #pragma unroll
        for (int q = 0; q < 4; ++q) {
            int idx = tid + q * 256;          // 1024 float4 total
            int row = idx >> 3;               // 8 float4 per row
            int kq = (idx & 7) << 2;
            float4 v = make_float4(0.f, 0.f, 0.f, 0.f);
            if (m0 + row < M)
                v = *reinterpret_cast<const float4*>(A + (size_t)(m0 + row) * 128 + k0 + kq);
            As[kq + 0][row] = v.x;
            As[kq + 1][row] = v.y;
            As[kq + 2][row] = v.z;
            As[kq + 3][row] = v.w;
        }
        // stage B: 32 k-rows x 128 cols
        #pragma unroll
        for (int q = 0; q < 4; ++q) {
            int idx = tid + q * 256;
            int r = idx >> 5;                 // 32 float4 per row
            int c4 = (idx & 31) << 2;
            float4 v = make_float4(0.f, 0.f, 0.f, 0.f);
            if (c4 + 3 < Ncols)
                v = *reinterpret_cast<const float4*>(B + (size_t)(k0 + r) * Ncols + c4);
            *reinterpret_cast<float4*>(&Bs[r][c4]) = v;
        }
        __syncthreads();

        #pragma unroll 8
        for (int kk = 0; kk < GBK; ++kk) {
            float4 alo = *reinterpret_cast<const float4*>(&As[kk][ty * 4]);
            float4 ahi = *reinterpret_cast<const float4*>(&As[kk][64 + ty * 4]);
            float4 blo = *reinterpret_cast<const float4*>(&Bs[kk][tx * 4]);
            float4 bhi = *reinterpret_cast<const float4*>(&Bs[kk][64 + tx * 4]);
            float av[8] = {alo.x, alo.y, alo.z, alo.w, ahi.x, ahi.y, ahi.z, ahi.w};
            float bv[8] = {blo.x, blo.y, blo.z, blo.w, bhi.x, bhi.y, bhi.z, bhi.w};
            #pragma unroll
            for (int i = 0; i < 8; ++i)
                #pragma unroll
                for (int j = 0; j < 8; ++j)
                    acc[i][j] += av[i] * bv[j];
        }
        __syncthreads();
    }

    // epilogue: rows {g*64 + ty*4 + i}, cols {g*64 + tx*4 + j}
    #pragma unroll
    for (int ri = 0; ri < 8; ++ri) {
        int row = m0 + ((ri >> 2) << 6) + ty * 4 + (ri & 3);
        if (row < M) {
            #pragma unroll
            for (int cg = 0; cg < 2; ++cg) {
                int col = (cg << 6) + tx * 4;
                if (col + 3 < Ncols) {
                    float4 v = make_float4(acc[ri][cg * 4 + 0], acc[ri][cg * 4 + 1],
                                           acc[ri][cg * 4 + 2], acc[ri][cg * 4 + 3]);
                    *reinterpret_cast<float4*>(C + (size_t)row * Ncols + col) = v;
                }
            }
        }
    }
}

// ---------------------------------------------------------------------------
// per-node attention logits: alS[n,h] = dot(hw[n,h,:], aS[h,:]) (aS flat 128)
// ---------------------------------------------------------------------------
__global__ __launch_bounds__(128) void al_kernel(const float* __restrict__ hw,
                                                 const float* __restrict__ aS,
                                                 const float* __restrict__ aD,
                                                 float* __restrict__ alS,
                                                 float* __restrict__ alD) {
    const int n = blockIdx.x;
    const int t = threadIdx.x;
    float v = hw[(size_t)n * 128 + t];
    float ps = v * aS[t];
    float pd = v * aD[t];
    #pragma unroll
    for (int o = 16; o > 0; o >>= 1) {
        ps += __shfl_xor(ps, o, 32);
        pd += __shfl_xor(pd, o, 32);
    }
    if ((t & 31) == 0) {
        int h = t >> 5;
        alS[n * 4 + h] = ps;
        alD[n * 4 + h] = pd;
    }
}

// ---------------------------------------------------------------------------
// softmax + aggregation, ONE WAVE PER NODE (4 nodes / 256-thread block).
// thread t (0..63) owns output cols t (head t>>5) and 64+t (head 2+(t>>5)).
// FINAL=0: out 128 wide, += bias + biasSk + skip, ELU
// FINAL=1: mean over heads, += ..., L2 normalize, out 32 wide
// ---------------------------------------------------------------------------
template <int FINAL>
__global__ __launch_bounds__(256) void agg_kernel(const int* __restrict__ off,
                                                  const int* __restrict__ csr,
                                                  const float* __restrict__ alS,
                                                  const float* __restrict__ alD,
                                                  const float* __restrict__ hw,
                                                  const float* __restrict__ hsk,
                                                  const float* __restrict__ bias,
                                                  const float* __restrict__ biasSk,
                                                  float* __restrict__ out) {
    const int node = blockIdx.x * 4 + (threadIdx.x >> 6);
    const int t = threadIdx.x & 63;
    const int start = off[node];
    const int end = off[node + 1];
    const int deg = end - start;
    const int h1 = t >> 5;          // 0 or 1
    const int h2 = h1 + 2;

    // ---- pass 1: per-head max. lane-task: slot = t>>2, head = t&3
    const int hh = t & 3;
    const float ad_hh = alD[(size_t)node * 4 + hh];
    float m = -INFINITY;
    for (int j0 = 0; j0 < deg; j0 += 16) {
        int j = j0 + (t >> 2);
        if (j < deg) {
            int s = csr[start + j];
            m = fmaxf(m, lrelu(alS[(size_t)s * 4 + hh] + ad_hh));
        }
    }
    m = fmaxf(m, __shfl_xor(m, 4, 64));
    m = fmaxf(m, __shfl_xor(m, 8, 64));
    m = fmaxf(m, __shfl_xor(m, 16, 64));
    m = fmaxf(m, __shfl_xor(m, 32, 64));
    // every lane now has max for head (t&3); pull the two heads this lane needs
    const float mA = __shfl(m, h1, 64);
    const float mB = __shfl(m, h2, 64);
    const float adA = alD[(size_t)node * 4 + h1];
    const float adB = alD[(size_t)node * 4 + h2];

    // ---- pass 2: exp-sum + weighted accumulate
    float acc0 = 0.f, acc1 = 0.f, sA = 0.f, sB = 0.f;
    int j = start;
    for (; j + 2 <= end; j += 2) {
        int s0 = csr[j], s1 = csr[j + 1];
        float a0A = alS[(size_t)s0 * 4 + h1];
        float a0B = alS[(size_t)s0 * 4 + h2];
        float a1A = alS[(size_t)s1 * 4 + h1];
        float a1B = alS[(size_t)s1 * 4 + h2];
        float h0l = hw[(size_t)s0 * 128 + t];
        float h0h = hw[(size_t)s0 * 128 + 64 + t];
        float h1l = hw[(size_t)s1 * 128 + t];
        float h1h = hw[(size_t)s1 * 128 + 64 + t];
        float x0A = __expf(lrelu(a0A + adA) - mA);
        float x0B = __expf(lrelu(a0B + adB) - mB);
        float x1A = __expf(lrelu(a1A + adA) - mA);
        float x1B = __expf(lrelu(a1B + adB) - mB);
        sA += x0A + x1A;
        sB += x0B + x1B;
        acc0 += x0A * h0l + x1A * h1l;
        acc1 += x0B * h0h + x1B * h1h;
    }
    if (j < end) {
        int s0 = csr[j];
        float a0A = alS[(size_t)s0 * 4 + h1];
        float a0B = alS[(size_t)s0 * 4 + h2];
        float h0l = hw[(size_t)s0 * 128 + t];
        float h0h = hw[(size_t)s0 * 128 + 64 + t];
        float x0A = __expf(lrelu(a0A + adA) - mA);
        float x0B = __expf(lrelu(a0B + adB) - mB);
        sA += x0A;
        sB += x0B;
        acc0 += x0A * h0l;
        acc1 += x0B * h0h;
    }

    float gA = acc0 / (sA + 1e-16f);
    float gB = acc1 / (sB + 1e-16f);

    if (FINAL == 0) {
        float v0 = gA + bias[t] + biasSk[t] + hsk[(size_t)node * 128 + t];
        float v1 = gB + bias[64 + t] + biasSk[64 + t] + hsk[(size_t)node * 128 + 64 + t];
        v0 = v0 > 0.f ? v0 : expm1f(v0);
        v1 = v1 > 0.f ? v1 : expm1f(v1);
        out[(size_t)node * 128 + t] = v0;
        out[(size_t)node * 128 + 64 + t] = v1;
    } else {
        // mean over heads: col c = t&31; combine lanes t<->t^32 and the two halves
        float sum1 = gA + __shfl_xor(gA, 32, 64);   // cols c, c+32
        float sum2 = gB + __shfl_xor(gB, 32, 64);   // cols c+64, c+96
        int c = t & 31;
        float v = (sum1 + sum2) * 0.25f + bias[c] + biasSk[c] + hsk[(size_t)node * 32 + c];
        float ss = v * v;
        #pragma unroll
        for (int o = 16; o > 0; o >>= 1) ss += __shfl_xor(ss, o, 32);
        float nrm = sqrtf(ss);
        if (t < 32) out[(size_t)node * 32 + c] = v / fmaxf(nrm, 1e-12f);
    }
}

// ---------------------------------------------------------------------------
// launch
// ---------------------------------------------------------------------------
extern "C" void kernel_launch(void* const* d_in, const int* in_sizes, int n_in,
                              void* d_out, int out_size, void* d_ws, size_t ws_size,
                              hipStream_t stream) {
    const float* x   = (const float*)d_in[0];
    const int*   ei  = (const int*)d_in[1];
    const float* W0  = (const float*)d_in[2];
    const float* aS0 = (const float*)d_in[3];
    const float* aD0 = (const float*)d_in[4];
    const float* b0  = (const float*)d_in[5];
    const float* Ws0 = (const float*)d_in[6];
    const float* bs0 = (const float*)d_in[7];
    const float* W1  = (const float*)d_in[8];
    const float* aS1 = (const float*)d_in[9];
    const float* aD1 = (const float*)d_in[10];
    const float* b1  = (const float*)d_in[11];
    const float* Ws1 = (const float*)d_in[12];
    const float* bs1 = (const float*)d_in[13];
    const float* W2  = (const float*)d_in[14];
    const float* aS2 = (const float*)d_in[15];
    const float* aD2 = (const float*)d_in[16];
    const float* b2  = (const float*)d_in[17];
    const float* Ws2 = (const float*)d_in[18];
    const float* bs2 = (const float*)d_in[19];
    float* out = (float*)d_out;

    char* p = (char*)d_ws;
    auto alloc = [&](size_t bytes) -> char* {
        char* q = p;
        p += (bytes + 255) & ~(size_t)255;
        return q;
    };
    int*   cnt  = (int*)alloc((size_t)NN * 4);
    int*   off  = (int*)alloc((size_t)(NN + 1) * 4);
    int*   csr  = (int*)alloc((size_t)NE * 4);
    float* hw   = (float*)alloc((size_t)NN * 128 * 4);
    float* hsk  = (float*)alloc((size_t)NN * 128 * 4);
    float* hbuf = (float*)alloc((size_t)NN * 128 * 4);
    float* alS  = (float*)alloc((size_t)NN * 4 * 4);
    float* alD  = (float*)alloc((size_t)NN * 4 * 4);

    const int EB = (NE + 255) / 256;
    const dim3 gg((NN + GBM - 1) / GBM, 2);   // (391, 2)
    const int AGGB = NN / 4;                  // 12500 blocks x 256 thr (4 nodes each)

    // CSR build (graph identical for all 3 layers)
    zero_kernel<<<(NN + 255) / 256, 256, 0, stream>>>(cnt, NN);
    count_kernel<<<EB, 256, 0, stream>>>(ei, cnt, NE);
    scan_kernel<<<1, 1024, 0, stream>>>(cnt, off, NN);
    fill_kernel<<<EB, 256, 0, stream>>>(ei, off, cnt, csr, NE);

    // ---- layer 0
    gemm_dual<<<gg, 256, 0, stream>>>(x, W0, hw, Ws0, hsk, NN, 128);
    al_kernel<<<NN, 128, 0, stream>>>(hw, aS0, aD0, alS, alD);
    agg_kernel<0><<<AGGB, 256, 0, stream>>>(off, csr, alS, alD, hw, hsk, b0, bs0, hbuf);

    // ---- layer 1
    gemm_dual<<<gg, 256, 0, stream>>>(hbuf, W1, hw, Ws1, hsk, NN, 128);
    al_kernel<<<NN, 128, 0, stream>>>(hw, aS1, aD1, alS, alD);
    agg_kernel<0><<<AGGB, 256, 0, stream>>>(off, csr, alS, alD, hw, hsk, b1, bs1, hbuf);

    // ---- layer 2 (Ws2 is [128,32] -> N2=32 path)
    gemm_dual<<<gg, 256, 0, stream>>>(hbuf, W2, hw, Ws2, hsk, NN, 32);
    al_kernel<<<NN, 128, 0, stream>>>(hw, aS2, aD2, alS, alD);
    agg_kernel<1><<<AGGB, 256, 0, stream>>>(off, csr, alS, alD, hw, hsk, b2, bs2, out);
}

// Round 3
// 507.536 us; speedup vs baseline: 1.3624x; 1.2702x over previous
//
#include <hip/hip_runtime.h>
#include <hip/hip_bf16.h>
#include <cstdint>
#include <cstddef>

#define NN 50000
#define NE 800000
#define NB 196   // ceil(NN/256)

typedef __attribute__((ext_vector_type(8))) short short8v;
typedef __attribute__((ext_vector_type(4))) float f32x4;
typedef unsigned short ushort_t;
typedef unsigned int uint_t;

// ---------------------------------------------------------------------------
// helpers
// ---------------------------------------------------------------------------
__device__ __forceinline__ float lrelu(float v) {
    return v > 0.f ? v : 0.2f * v;
}
__device__ __forceinline__ ushort_t f2bf(float f) {
    __hip_bfloat16 h = __float2bfloat16(f);
    return *reinterpret_cast<ushort_t*>(&h);
}
__device__ __forceinline__ float bf2f(ushort_t u) {
    return __uint_as_float(((uint_t)u) << 16);
}
__device__ __forceinline__ float bflo(uint_t u) { return __uint_as_float(u << 16); }
__device__ __forceinline__ float bfhi(uint_t u) { return __uint_as_float(u & 0xffff0000u); }

// ---------------------------------------------------------------------------
// conversions: x -> bf16; W [K=128][N] -> Wt bf16 [N][128]
// ---------------------------------------------------------------------------
__global__ __launch_bounds__(256) void cvt_kernel(const float* __restrict__ in,
                                                  ushort_t* __restrict__ out, int n4) {
    int i = blockIdx.x * 256 + threadIdx.x;   // over groups of 4
    if (i < n4) {
        float4 v = *reinterpret_cast<const float4*>(in + (size_t)i * 4);
        uint_t u0 = (uint_t)f2bf(v.x) | ((uint_t)f2bf(v.y) << 16);
        uint_t u1 = (uint_t)f2bf(v.z) | ((uint_t)f2bf(v.w) << 16);
        uint2 p = make_uint2(u0, u1);
        *reinterpret_cast<uint2*>(out + (size_t)i * 4) = p;
    }
}

__global__ __launch_bounds__(256) void wcvt_kernel(const float* __restrict__ W,
                                                   ushort_t* __restrict__ Wt, int nlog) {
    int i = blockIdx.x * 256 + threadIdx.x;   // over 128*N
    int total = 128 << nlog;
    if (i < total) {
        int k = i >> nlog;
        int n = i & ((1 << nlog) - 1);
        Wt[(size_t)n * 128 + k] = f2bf(W[i]);
    }
}

// ---------------------------------------------------------------------------
// CSR build: zero -> count -> 3-kernel parallel scan -> fill
// ---------------------------------------------------------------------------
__global__ void zero_kernel(int* __restrict__ p, int n) {
    int i = blockIdx.x * blockDim.x + threadIdx.x;
    if (i < n) p[i] = 0;
}

__global__ void count_kernel(const int* __restrict__ ei, int* __restrict__ cnt, int E) {
    int e = blockIdx.x * blockDim.x + threadIdx.x;
    if (e < E) atomicAdd(&cnt[ei[E + e]], 1);
}

__global__ __launch_bounds__(256) void psum_kernel(const int* __restrict__ cnt,
                                                   int* __restrict__ bsum) {
    int i = blockIdx.x * 256 + threadIdx.x;
    int v = (i < NN) ? cnt[i] : 0;
    #pragma unroll
    for (int o = 1; o < 64; o <<= 1) v += __shfl_xor(v, o, 64);
    __shared__ int ws[4];
    if ((threadIdx.x & 63) == 0) ws[threadIdx.x >> 6] = v;
    __syncthreads();
    if (threadIdx.x == 0) bsum[blockIdx.x] = ws[0] + ws[1] + ws[2] + ws[3];
}

__global__ __launch_bounds__(256) void bscan_kernel(const int* __restrict__ bsum,
                                                    int* __restrict__ bpre) {
    int t = threadIdx.x;
    int lane = t & 63, w = t >> 6;
    int v = (t < NB) ? bsum[t] : 0;
    int x = v;
    #pragma unroll
    for (int o = 1; o < 64; o <<= 1) {
        int y = __shfl_up(x, o, 64);
        if (lane >= o) x += y;
    }
    __shared__ int ws[4];
    if (lane == 63) ws[w] = x;
    __syncthreads();
    if (t == 0) {
        int s = 0;
        #pragma unroll
        for (int q = 0; q < 4; ++q) { int tmp = ws[q]; ws[q] = s; s += tmp; }
    }
    __syncthreads();
    if (t < NB) bpre[t] = (x - v) + ws[w];   // exclusive prefix
}

__global__ __launch_bounds__(256) void scan3_kernel(int* __restrict__ cnt,
                                                    const int* __restrict__ bpre,
                                                    int* __restrict__ off) {
    int b = blockIdx.x, t = threadIdx.x;
    int i = b * 256 + t;
    int lane = t & 63, w = t >> 6;
    int v = (i < NN) ? cnt[i] : 0;
    if (i < NN) cnt[i] = 0;                  // reuse as fill cursor
    int x = v;
    #pragma unroll
    for (int o = 1; o < 64; o <<= 1) {
        int y = __shfl_up(x, o, 64);
        if (lane >= o) x += y;
    }
    __shared__ int ws[4];
    if (lane == 63) ws[w] = x;
    __syncthreads();
    if (t == 0) {
        int s = 0;
        #pragma unroll
        for (int q = 0; q < 4; ++q) { int tmp = ws[q]; ws[q] = s; s += tmp; }
    }
    __syncthreads();
    int incl = x + ws[w];
    if (i < NN) off[i + 1] = bpre[b] + incl;
    if (i == 0) off[0] = 0;
}

__global__ void fill_kernel(const int* __restrict__ ei, const int* __restrict__ off,
                            int* __restrict__ cursor, int* __restrict__ csr, int E) {
    int e = blockIdx.x * blockDim.x + threadIdx.x;
    if (e < E) {
        int s = ei[e];
        int d = ei[E + e];
        int pos = off[d] + atomicAdd(&cursor[d], 1);
        csr[pos] = s;
    }
}

// ---------------------------------------------------------------------------
// MFMA GEMM, K=128. A bf16 [M][128]. Bt bf16 [N][128] (pre-transposed).
// y=0: C1 = A@B1 -> bf16, N=128.  y=1: C2 = A@B2 -> fp32, N=N2 (128 or 32).
// Block 256 thr = 4 waves; block tile 128 rows x 64..128 cols; no LDS.
// Wave w: rows m0+(w&1)*64, cols (w>>1)*64; per wave 4x4 frags of 16x16, 4 K-steps.
// Frag layouts (16x16x32 bf16): A lane: row=l&15, k=(l>>4)*8+j ;
// B lane: col=l&15, k=(l>>4)*8+j ; C/D: col=l&15, row=(l>>4)*4+reg  [m89/m91]
// ---------------------------------------------------------------------------
__global__ __launch_bounds__(256) void gemm_mfma(const ushort_t* __restrict__ A,
                                                 const ushort_t* __restrict__ Bt1,
                                                 ushort_t* __restrict__ C1,
                                                 const ushort_t* __restrict__ Bt2,
                                                 float* __restrict__ C2,
                                                 int M, int N2) {
    const int tid = threadIdx.x;
    const int wave = tid >> 6;
    const int lane = tid & 63;
    const bool second = (blockIdx.y == 1);
    const ushort_t* __restrict__ Bt = second ? Bt2 : Bt1;
    const int Ncols = second ? N2 : 128;

    const int m0 = blockIdx.x * 128 + (wave & 1) * 64;
    const int c0 = (wave >> 1) * 64;
    if (c0 >= Ncols) return;
    const int nF = (Ncols - c0) >= 64 ? 4 : ((Ncols - c0) >> 4);

    const int l15 = lane & 15;
    const int kg8 = (lane >> 4) * 8;

    const ushort_t* ap[4];
    const ushort_t* bp[4];
    #pragma unroll
    for (int fm = 0; fm < 4; ++fm) {
        int row = m0 + fm * 16 + l15;
        row = row < M ? row : (M - 1);        // clamp; tail rows not stored
        ap[fm] = A + (size_t)row * 128 + kg8;
    }
    #pragma unroll
    for (int fn = 0; fn < 4; ++fn) {
        int col = c0 + fn * 16 + l15;
        col = fn < nF ? col : 0;
        bp[fn] = Bt + (size_t)col * 128 + kg8;
    }

    f32x4 acc[4][4];
    #pragma unroll
    for (int i = 0; i < 4; ++i)
        #pragma unroll
        for (int j = 0; j < 4; ++j) acc[i][j] = (f32x4){0.f, 0.f, 0.f, 0.f};

    #pragma unroll
    for (int ks = 0; ks < 4; ++ks) {
        short8v a[4], b[4];
        #pragma unroll
        for (int fm = 0; fm < 4; ++fm)
            a[fm] = *reinterpret_cast<const short8v*>(ap[fm] + ks * 32);
        #pragma unroll
        for (int fn = 0; fn < 4; ++fn)
            if (fn < nF)
                b[fn] = *reinterpret_cast<const short8v*>(bp[fn] + ks * 32);
        #pragma unroll
        for (int fm = 0; fm < 4; ++fm)
            #pragma unroll
            for (int fn = 0; fn < 4; ++fn)
                if (fn < nF)
                    acc[fm][fn] = __builtin_amdgcn_mfma_f32_16x16x32_bf16(
                        a[fm], b[fn], acc[fm][fn], 0, 0, 0);
    }

    const int rbase = (lane >> 4) * 4;
    #pragma unroll
    for (int fm = 0; fm < 4; ++fm) {
        #pragma unroll
        for (int r = 0; r < 4; ++r) {
            int row = m0 + fm * 16 + rbase + r;
            if (row < M) {
                #pragma unroll
                for (int fn = 0; fn < 4; ++fn) {
                    if (fn < nF) {
                        int col = c0 + fn * 16 + l15;
                        float v = acc[fm][fn][r];
                        if (second) C2[(size_t)row * Ncols + col] = v;
                        else        C1[(size_t)row * 128 + col] = f2bf(v);
                    }
                }
            }
        }
    }
}

// ---------------------------------------------------------------------------
// attention logits from bf16 hw
// ---------------------------------------------------------------------------
__global__ __launch_bounds__(128) void al_kernel(const ushort_t* __restrict__ hwB,
                                                 const float* __restrict__ aS,
                                                 const float* __restrict__ aD,
                                                 float* __restrict__ alS,
                                                 float* __restrict__ alD) {
    const int n = blockIdx.x;
    const int t = threadIdx.x;
    float v = bf2f(hwB[(size_t)n * 128 + t]);
    float ps = v * aS[t];
    float pd = v * aD[t];
    #pragma unroll
    for (int o = 16; o > 0; o >>= 1) {
        ps += __shfl_xor(ps, o, 32);
        pd += __shfl_xor(pd, o, 32);
    }
    if ((t & 31) == 0) {
        int h = t >> 5;
        alS[n * 4 + h] = ps;
        alD[n * 4 + h] = pd;
    }
}

// ---------------------------------------------------------------------------
// softmax + aggregation, one wave per node (4 nodes / 256-thr block).
// lane t owns cols 2t, 2t+1 (both head h = t>>4) -> ONE dword (2x bf16) per edge.
// FINAL=0: out bf16 [N][128] (+bias+skip, ELU).  FINAL=1: head-mean, +skip,
// L2-normalize, out fp32 [N][32].
// ---------------------------------------------------------------------------
template <int FINAL>
__global__ __launch_bounds__(256) void agg_kernel(const int* __restrict__ off,
                                                  const int* __restrict__ csr,
                                                  const float* __restrict__ alS,
                                                  const float* __restrict__ alD,
                                                  const ushort_t* __restrict__ hwB,
                                                  const float* __restrict__ hsk,
                                                  const float* __restrict__ bias,
                                                  const float* __restrict__ biasSk,
                                                  void* __restrict__ outp) {
    const int node = blockIdx.x * 4 + (threadIdx.x >> 6);
    const int t = threadIdx.x & 63;
    const int start = off[node];
    const int end = off[node + 1];
    const int deg = end - start;
    const int h = t >> 4;                      // head this lane aggregates

    // ---- pass 1: per-head max. lane-task: slot = t>>2 (16 slots), head = t&3
    const int hh = t & 3;
    const float ad_hh = alD[(size_t)node * 4 + hh];
    float m = -INFINITY;
    for (int j0 = 0; j0 < deg; j0 += 16) {
        int j = j0 + (t >> 2);
        if (j < deg) {
            int s = csr[start + j];
            m = fmaxf(m, lrelu(alS[(size_t)s * 4 + hh] + ad_hh));
        }
    }
    m = fmaxf(m, __shfl_xor(m, 4, 64));
    m = fmaxf(m, __shfl_xor(m, 8, 64));
    m = fmaxf(m, __shfl_xor(m, 16, 64));
    m = fmaxf(m, __shfl_xor(m, 32, 64));
    const float mH = __shfl(m, h, 64);         // lanes 0..3 hold heads 0..3
    const float adH = alD[(size_t)node * 4 + h];

    // ---- pass 2: exp-sum + weighted accumulate (coalesced dword hw loads)
    const uint_t* __restrict__ hw32 = reinterpret_cast<const uint_t*>(hwB);
    float acc0 = 0.f, acc1 = 0.f, sA = 0.f;
    int j = start;
    for (; j + 2 <= end; j += 2) {
        int s0 = csr[j], s1 = csr[j + 1];
        float a0 = alS[(size_t)s0 * 4 + h];
        float a1 = alS[(size_t)s1 * 4 + h];
        uint_t u0 = hw32[(size_t)s0 * 64 + t];
        uint_t u1 = hw32[(size_t)s1 * 64 + t];
        float e0 = __expf(lrelu(a0 + adH) - mH);
        float e1 = __expf(lrelu(a1 + adH) - mH);
        sA += e0 + e1;
        acc0 += e0 * bflo(u0) + e1 * bflo(u1);
        acc1 += e0 * bfhi(u0) + e1 * bfhi(u1);
    }
    if (j < end) {
        int s0 = csr[j];
        float a0 = alS[(size_t)s0 * 4 + h];
        uint_t u0 = hw32[(size_t)s0 * 64 + t];
        float e0 = __expf(lrelu(a0 + adH) - mH);
        sA += e0;
        acc0 += e0 * bflo(u0);
        acc1 += e0 * bfhi(u0);
    }

    const float inv = 1.f / (sA + 1e-16f);
    float g0 = acc0 * inv;                      // col 2t
    float g1 = acc1 * inv;                      // col 2t+1

    if (FINAL == 0) {
        ushort_t* outB = reinterpret_cast<ushort_t*>(outp);
        int c0 = 2 * t;
        float2 sk = *reinterpret_cast<const float2*>(hsk + (size_t)node * 128 + c0);
        float v0 = g0 + bias[c0] + biasSk[c0] + sk.x;
        float v1 = g1 + bias[c0 + 1] + biasSk[c0 + 1] + sk.y;
        v0 = v0 > 0.f ? v0 : expm1f(v0);
        v1 = v1 > 0.f ? v1 : expm1f(v1);
        uint_t pack = (uint_t)f2bf(v0) | ((uint_t)f2bf(v1) << 16);
        reinterpret_cast<uint_t*>(outB)[(size_t)node * 64 + t] = pack;
    } else {
        float* out = reinterpret_cast<float*>(outp);
        // head-mean: col c held across lanes {t, t^16, t^32, t^48}
        float s0v = g0 + __shfl_xor(g0, 16, 64);
        s0v += __shfl_xor(s0v, 32, 64);
        float s1v = g1 + __shfl_xor(g1, 16, 64);
        s1v += __shfl_xor(s1v, 32, 64);
        if (t < 16) {
            int c0 = 2 * t, c1 = 2 * t + 1;
            float v0 = s0v * 0.25f + bias[c0] + biasSk[c0] + hsk[(size_t)node * 32 + c0];
            float v1 = s1v * 0.25f + bias[c1] + biasSk[c1] + hsk[(size_t)node * 32 + c1];
            float ss = v0 * v0 + v1 * v1;
            #pragma unroll
            for (int o = 8; o > 0; o >>= 1) ss += __shfl_xor(ss, o, 64);
            float r = 1.f / fmaxf(sqrtf(ss), 1e-12f);
            float2 w = make_float2(v0 * r, v1 * r);
            *reinterpret_cast<float2*>(out + (size_t)node * 32 + c0) = w;
        }
    }
}

// ---------------------------------------------------------------------------
// launch
// ---------------------------------------------------------------------------
extern "C" void kernel_launch(void* const* d_in, const int* in_sizes, int n_in,
                              void* d_out, int out_size, void* d_ws, size_t ws_size,
                              hipStream_t stream) {
    const float* x   = (const float*)d_in[0];
    const int*   ei  = (const int*)d_in[1];
    const float* W0  = (const float*)d_in[2];
    const float* aS0 = (const float*)d_in[3];
    const float* aD0 = (const float*)d_in[4];
    const float* b0  = (const float*)d_in[5];
    const float* Ws0 = (const float*)d_in[6];
    const float* bs0 = (const float*)d_in[7];
    const float* W1  = (const float*)d_in[8];
    const float* aS1 = (const float*)d_in[9];
    const float* aD1 = (const float*)d_in[10];
    const float* b1  = (const float*)d_in[11];
    const float* Ws1 = (const float*)d_in[12];
    const float* bs1 = (const float*)d_in[13];
    const float* W2  = (const float*)d_in[14];
    const float* aS2 = (const float*)d_in[15];
    const float* aD2 = (const float*)d_in[16];
    const float* b2  = (const float*)d_in[17];
    const float* Ws2 = (const float*)d_in[18];
    const float* bs2 = (const float*)d_in[19];
    float* out = (float*)d_out;

    char* p = (char*)d_ws;
    auto alloc = [&](size_t bytes) -> char* {
        char* q = p;
        p += (bytes + 255) & ~(size_t)255;
        return q;
    };
    int*      cnt   = (int*)alloc((size_t)NN * 4);
    int*      off   = (int*)alloc((size_t)(NN + 1) * 4);
    int*      csr   = (int*)alloc((size_t)NE * 4);
    int*      bsum  = (int*)alloc((size_t)NB * 4);
    int*      bpre  = (int*)alloc((size_t)NB * 4);
    ushort_t* xb    = (ushort_t*)alloc((size_t)NN * 128 * 2);
    ushort_t* hwB   = (ushort_t*)alloc((size_t)NN * 128 * 2);
    ushort_t* hbufB = (ushort_t*)alloc((size_t)NN * 128 * 2);
    float*    hsk   = (float*)alloc((size_t)NN * 128 * 4);
    float*    alS   = (float*)alloc((size_t)NN * 4 * 4);
    float*    alD   = (float*)alloc((size_t)NN * 4 * 4);
    ushort_t* Wt0   = (ushort_t*)alloc((size_t)128 * 128 * 2);
    ushort_t* Wts0  = (ushort_t*)alloc((size_t)128 * 128 * 2);
    ushort_t* Wt1   = (ushort_t*)alloc((size_t)128 * 128 * 2);
    ushort_t* Wts1  = (ushort_t*)alloc((size_t)128 * 128 * 2);
    ushort_t* Wt2   = (ushort_t*)alloc((size_t)128 * 128 * 2);
    ushort_t* Wts2  = (ushort_t*)alloc((size_t)32 * 128 * 2);

    const int EB = (NE + 255) / 256;
    const dim3 gg((NN + 127) / 128, 2);   // (391, 2)
    const int AGGB = NN / 4;

    // conversions
    cvt_kernel<<<(NN * 128 / 4 + 255) / 256, 256, 0, stream>>>(x, xb, NN * 128 / 4);
    wcvt_kernel<<<64, 256, 0, stream>>>(W0, Wt0, 7);
    wcvt_kernel<<<64, 256, 0, stream>>>(Ws0, Wts0, 7);
    wcvt_kernel<<<64, 256, 0, stream>>>(W1, Wt1, 7);
    wcvt_kernel<<<64, 256, 0, stream>>>(Ws1, Wts1, 7);
    wcvt_kernel<<<64, 256, 0, stream>>>(W2, Wt2, 7);
    wcvt_kernel<<<16, 256, 0, stream>>>(Ws2, Wts2, 5);

    // CSR build
    zero_kernel<<<(NN + 255) / 256, 256, 0, stream>>>(cnt, NN);
    count_kernel<<<EB, 256, 0, stream>>>(ei, cnt, NE);
    psum_kernel<<<NB, 256, 0, stream>>>(cnt, bsum);
    bscan_kernel<<<1, 256, 0, stream>>>(bsum, bpre);
    scan3_kernel<<<NB, 256, 0, stream>>>(cnt, bpre, off);
    fill_kernel<<<EB, 256, 0, stream>>>(ei, off, cnt, csr, NE);

    // ---- layer 0
    gemm_mfma<<<gg, 256, 0, stream>>>(xb, Wt0, hwB, Wts0, hsk, NN, 128);
    al_kernel<<<NN, 128, 0, stream>>>(hwB, aS0, aD0, alS, alD);
    agg_kernel<0><<<AGGB, 256, 0, stream>>>(off, csr, alS, alD, hwB, hsk, b0, bs0, hbufB);

    // ---- layer 1
    gemm_mfma<<<gg, 256, 0, stream>>>(hbufB, Wt1, hwB, Wts1, hsk, NN, 128);
    al_kernel<<<NN, 128, 0, stream>>>(hwB, aS1, aD1, alS, alD);
    agg_kernel<0><<<AGGB, 256, 0, stream>>>(off, csr, alS, alD, hwB, hsk, b1, bs1, hbufB);

    // ---- layer 2 (skip GEMM N2=32; head-mean + L2 normalize)
    gemm_mfma<<<gg, 256, 0, stream>>>(hbufB, Wt2, hwB, Wts2, hsk, NN, 32);
    al_kernel<<<NN, 128, 0, stream>>>(hwB, aS2, aD2, alS, alD);
    agg_kernel<1><<<AGGB, 256, 0, stream>>>(off, csr, alS, alD, hwB, hsk, b2, bs2, out);
}

// Round 4
// 447.794 us; speedup vs baseline: 1.5442x; 1.1334x over previous
//
#include <hip/hip_runtime.h>
#include <hip/hip_bf16.h>
#include <cstdint>
#include <cstddef>

#define NN 50000
#define NE 800000
#define NB 196   // ceil(NN/256)

typedef __attribute__((ext_vector_type(8))) short short8v;
typedef __attribute__((ext_vector_type(4))) float f32x4;
typedef unsigned short ushort_t;
typedef unsigned int uint_t;

// ---------------------------------------------------------------------------
// helpers
// ---------------------------------------------------------------------------
__device__ __forceinline__ float lrelu(float v) {
    return v > 0.f ? v : 0.2f * v;
}
__device__ __forceinline__ ushort_t f2bf(float f) {
    __hip_bfloat16 h = __float2bfloat16(f);
    return *reinterpret_cast<ushort_t*>(&h);
}
__device__ __forceinline__ float bflo(uint_t u) { return __uint_as_float(u << 16); }
__device__ __forceinline__ float bfhi(uint_t u) { return __uint_as_float(u & 0xffff0000u); }

// ---------------------------------------------------------------------------
// all weight conversions in ONE kernel: W [128][N] fp32 -> Wt bf16 [N][128]
// ---------------------------------------------------------------------------
__global__ __launch_bounds__(256) void wcvt_all(
    const float* __restrict__ W0, const float* __restrict__ Ws0,
    const float* __restrict__ W1, const float* __restrict__ Ws1,
    const float* __restrict__ W2, const float* __restrict__ Ws2,
    ushort_t* __restrict__ T0, ushort_t* __restrict__ Ts0,
    ushort_t* __restrict__ T1, ushort_t* __restrict__ Ts1,
    ushort_t* __restrict__ T2, ushort_t* __restrict__ Ts2) {
    int idx = blockIdx.x * 256 + threadIdx.x;
    if (idx < 81920) {
        int m = idx >> 14;          // which 128x128 matrix
        int i = idx & 16383;
        const float* src; ushort_t* dst;
        switch (m) {
            case 0: src = W0;  dst = T0;  break;
            case 1: src = Ws0; dst = Ts0; break;
            case 2: src = W1;  dst = T1;  break;
            case 3: src = Ws1; dst = Ts1; break;
            default: src = W2; dst = T2;  break;
        }
        int k = i >> 7, n = i & 127;
        dst[n * 128 + k] = f2bf(src[i]);
    } else {
        int i = idx - 81920;        // 4096 elems of Ws2 [128][32]
        int k = i >> 5, n = i & 31;
        Ts2[n * 128 + k] = f2bf(Ws2[i]);
    }
}

// ---------------------------------------------------------------------------
// CSR build: zero -> count -> 3-kernel parallel scan -> fill
// ---------------------------------------------------------------------------
__global__ void zero_kernel(int* __restrict__ p, int n) {
    int i = blockIdx.x * blockDim.x + threadIdx.x;
    if (i < n) p[i] = 0;
}

__global__ void count_kernel(const int* __restrict__ ei, int* __restrict__ cnt, int E) {
    int e = blockIdx.x * blockDim.x + threadIdx.x;
    if (e < E) atomicAdd(&cnt[ei[E + e]], 1);
}

__global__ __launch_bounds__(256) void psum_kernel(const int* __restrict__ cnt,
                                                   int* __restrict__ bsum) {
    int i = blockIdx.x * 256 + threadIdx.x;
    int v = (i < NN) ? cnt[i] : 0;
    #pragma unroll
    for (int o = 1; o < 64; o <<= 1) v += __shfl_xor(v, o, 64);
    __shared__ int ws[4];
    if ((threadIdx.x & 63) == 0) ws[threadIdx.x >> 6] = v;
    __syncthreads();
    if (threadIdx.x == 0) bsum[blockIdx.x] = ws[0] + ws[1] + ws[2] + ws[3];
}

__global__ __launch_bounds__(256) void bscan_kernel(const int* __restrict__ bsum,
                                                    int* __restrict__ bpre) {
    int t = threadIdx.x;
    int lane = t & 63, w = t >> 6;
    int v = (t < NB) ? bsum[t] : 0;
    int x = v;
    #pragma unroll
    for (int o = 1; o < 64; o <<= 1) {
        int y = __shfl_up(x, o, 64);
        if (lane >= o) x += y;
    }
    __shared__ int ws[4];
    if (lane == 63) ws[w] = x;
    __syncthreads();
    if (t == 0) {
        int s = 0;
        #pragma unroll
        for (int q = 0; q < 4; ++q) { int tmp = ws[q]; ws[q] = s; s += tmp; }
    }
    __syncthreads();
    if (t < NB) bpre[t] = (x - v) + ws[w];
}

__global__ __launch_bounds__(256) void scan3_kernel(int* __restrict__ cnt,
                                                    const int* __restrict__ bpre,
                                                    int* __restrict__ off) {
    int b = blockIdx.x, t = threadIdx.x;
    int i = b * 256 + t;
    int lane = t & 63, w = t >> 6;
    int v = (i < NN) ? cnt[i] : 0;
    if (i < NN) cnt[i] = 0;                  // reuse as fill cursor
    int x = v;
    #pragma unroll
    for (int o = 1; o < 64; o <<= 1) {
        int y = __shfl_up(x, o, 64);
        if (lane >= o) x += y;
    }
    __shared__ int ws[4];
    if (lane == 63) ws[w] = x;
    __syncthreads();
    if (t == 0) {
        int s = 0;
        #pragma unroll
        for (int q = 0; q < 4; ++q) { int tmp = ws[q]; ws[q] = s; s += tmp; }
    }
    __syncthreads();
    int incl = x + ws[w];
    if (i < NN) off[i + 1] = bpre[b] + incl;
    if (i == 0) off[0] = 0;
}

__global__ void fill_kernel(const int* __restrict__ ei, const int* __restrict__ off,
                            int* __restrict__ cursor, int* __restrict__ csr, int E) {
    int e = blockIdx.x * blockDim.x + threadIdx.x;
    if (e < E) {
        int s = ei[e];
        int d = ei[E + e];
        int pos = off[d] + atomicAdd(&cursor[d], 1);
        csr[pos] = s;
    }
}

// ---------------------------------------------------------------------------
// LDS-staged MFMA GEMM + fused attention-logit epilogue. K=128 fixed.
// A: fp32 [M][128] (AFP32=1) or bf16 [M][128] (AFP32=0).
// y=0: C1 = A@B1^T -> bf16 [M][128], plus alS/alD = (A@B1)·aS/aD per head.
// y=1: C2 = A@B2^T -> fp32 [M][N2] (N2 = 128 or 32).
// LDS: A tile 128x128 bf16 (32KB) + B tile (32KB), XOR swizzle bits 4..6 by row
// so stride-256B frag ds_read_b128 is 2-way (free) instead of 16-way conflict.
// ---------------------------------------------------------------------------
template <int AFP32>
__global__ __launch_bounds__(256) void gemm_fused(const void* __restrict__ Ap,
                                                  const ushort_t* __restrict__ Bt1,
                                                  ushort_t* __restrict__ C1,
                                                  const ushort_t* __restrict__ Bt2,
                                                  float* __restrict__ C2,
                                                  const float* __restrict__ aS,
                                                  const float* __restrict__ aD,
                                                  float* __restrict__ alS,
                                                  float* __restrict__ alD,
                                                  int M, int N2) {
    __shared__ ushort_t As[128 * 128];   // 32KB swizzled
    __shared__ ushort_t Bs[128 * 128];   // 32KB swizzled
    const int tid = threadIdx.x;
    const int wave = tid >> 6;
    const int lane = tid & 63;
    const int l15 = lane & 15;
    const int kg = lane >> 4;            // 0..3
    const bool second = (blockIdx.y == 1);
    const int m0 = blockIdx.x * 128;
    const int Ncols = second ? N2 : 128;

    // ---- stage A (coalesced, swizzled write)
    if (AFP32) {
        const float* A = (const float*)Ap;
        const int c = tid & 31;          // 8B dest chunk / 16B src chunk
        #pragma unroll
        for (int q = 0; q < 16; ++q) {
            int row = (tid >> 5) + q * 8;
            int sr = m0 + row; sr = sr < M ? sr : M - 1;
            float4 v = *reinterpret_cast<const float4*>(A + (size_t)sr * 128 + c * 4);
            uint_t u0 = (uint_t)f2bf(v.x) | ((uint_t)f2bf(v.y) << 16);
            uint_t u1 = (uint_t)f2bf(v.z) | ((uint_t)f2bf(v.w) << 16);
            int bo = row * 256 + ((c * 8) ^ ((row & 7) << 4));
            *reinterpret_cast<uint2*>(reinterpret_cast<char*>(As) + bo) = make_uint2(u0, u1);
        }
    } else {
        const ushort_t* A = (const ushort_t*)Ap;
        const int c = tid & 15;          // 16B chunk
        #pragma unroll
        for (int q = 0; q < 8; ++q) {
            int row = (tid >> 4) + q * 16;
            int sr = m0 + row; sr = sr < M ? sr : M - 1;
            uint4 v = *reinterpret_cast<const uint4*>(A + (size_t)sr * 128 + c * 8);
            int bo = row * 256 + ((c * 16) ^ ((row & 7) << 4));
            *reinterpret_cast<uint4*>(reinterpret_cast<char*>(As) + bo) = v;
        }
    }
    // ---- stage B (rows of Bt = output cols)
    {
        const ushort_t* Bt = second ? Bt2 : Bt1;
        const int c = tid & 15;
        for (int row = tid >> 4; row < Ncols; row += 16) {
            uint4 v = *reinterpret_cast<const uint4*>(Bt + (size_t)row * 128 + c * 8);
            int bo = row * 256 + ((c * 16) ^ ((row & 7) << 4));
            *reinterpret_cast<uint4*>(reinterpret_cast<char*>(Bs) + bo) = v;
        }
    }
    __syncthreads();

    const int r0 = (wave & 1) * 64;      // tile-local row base for this wave
    const int c0 = (wave >> 1) * 64;     // col base
    if (c0 >= Ncols) return;
    const int nF = (Ncols - c0) >= 64 ? 4 : ((Ncols - c0) >> 4);

    f32x4 acc[4][4];
    #pragma unroll
    for (int i = 0; i < 4; ++i)
        #pragma unroll
        for (int j = 0; j < 4; ++j) acc[i][j] = (f32x4){0.f, 0.f, 0.f, 0.f};

    #pragma unroll
    for (int ks = 0; ks < 4; ++ks) {
        const int kb = kg * 16 + ks * 64;   // frag k byte offset
        short8v a[4], b[4];
        #pragma unroll
        for (int fm = 0; fm < 4; ++fm) {
            int row = r0 + fm * 16 + l15;
            int bo = row * 256 + (kb ^ ((row & 7) << 4));
            a[fm] = *reinterpret_cast<const short8v*>(reinterpret_cast<const char*>(As) + bo);
        }
        #pragma unroll
        for (int fn = 0; fn < 4; ++fn) {
            if (fn < nF) {
                int row = c0 + fn * 16 + l15;
                int bo = row * 256 + (kb ^ ((row & 7) << 4));
                b[fn] = *reinterpret_cast<const short8v*>(reinterpret_cast<const char*>(Bs) + bo);
            }
        }
        #pragma unroll
        for (int fm = 0; fm < 4; ++fm)
            #pragma unroll
            for (int fn = 0; fn < 4; ++fn)
                if (fn < nF)
                    acc[fm][fn] = __builtin_amdgcn_mfma_f32_16x16x32_bf16(
                        a[fm], b[fn], acc[fm][fn], 0, 0, 0);
    }

    // ---- C write.  C/D frag: col = l15, row = kg*4 + reg  [m89/m91]
    #pragma unroll
    for (int fm = 0; fm < 4; ++fm) {
        #pragma unroll
        for (int r = 0; r < 4; ++r) {
            int row = m0 + r0 + fm * 16 + kg * 4 + r;
            if (row < M) {
                #pragma unroll
                for (int fn = 0; fn < 4; ++fn) {
                    if (fn < nF) {
                        int col = c0 + fn * 16 + l15;
                        float v = acc[fm][fn][r];
                        if (second) C2[(size_t)row * Ncols + col] = v;
                        else        C1[(size_t)row * 128 + col] = f2bf(v);
                    }
                }
            }
        }
    }

    // ---- fused attention-logit epilogue (y=0 only): alS/alD from fp32 acc
    if (!second) {
        float aSv[4], aDv[4];
        #pragma unroll
        for (int fn = 0; fn < 4; ++fn) {
            aSv[fn] = aS[c0 + fn * 16 + l15];
            aDv[fn] = aD[c0 + fn * 16 + l15];
        }
        const int hb = c0 >> 5;          // head base: 0 or 2
        #pragma unroll
        for (int fm = 0; fm < 4; ++fm) {
            #pragma unroll
            for (int r = 0; r < 4; ++r) {
                float s0 = acc[fm][0][r] * aSv[0] + acc[fm][1][r] * aSv[1];
                float s1 = acc[fm][2][r] * aSv[2] + acc[fm][3][r] * aSv[3];
                float d0 = acc[fm][0][r] * aDv[0] + acc[fm][1][r] * aDv[1];
                float d1 = acc[fm][2][r] * aDv[2] + acc[fm][3][r] * aDv[3];
                #pragma unroll
                for (int o = 1; o < 16; o <<= 1) {
                    s0 += __shfl_xor(s0, o, 64);
                    s1 += __shfl_xor(s1, o, 64);
                    d0 += __shfl_xor(d0, o, 64);
                    d1 += __shfl_xor(d1, o, 64);
                }
                if (l15 == 0) {
                    int row = m0 + r0 + fm * 16 + kg * 4 + r;
                    if (row < M) {
                        *reinterpret_cast<float2*>(alS + (size_t)row * 4 + hb) = make_float2(s0, s1);
                        *reinterpret_cast<float2*>(alD + (size_t)row * 4 + hb) = make_float2(d0, d1);
                    }
                }
            }
        }
    }
}

// ---------------------------------------------------------------------------
// softmax + aggregation, one wave per node (4 nodes / 256-thr block).
// 16-lane groups: group eo = t>>4 handles edge j+eo (4 edges per iteration);
// lane g = t&15 owns cols g*8..g*8+7 (head g>>2) via one dwordx4 (8 bf16).
// No max-subtraction (softmax shift-invariant; logits are O(5)).
// FINAL=0: out bf16 [N][128] (+bias+skip, ELU).  FINAL=1: head-mean, +skip,
// L2-normalize, out fp32 [N][32].
// ---------------------------------------------------------------------------
template <int FINAL>
__global__ __launch_bounds__(256) void agg_kernel(const int* __restrict__ off,
                                                  const int* __restrict__ csr,
                                                  const float* __restrict__ alS,
                                                  const float* __restrict__ alD,
                                                  const ushort_t* __restrict__ hwB,
                                                  const float* __restrict__ hsk,
                                                  const float* __restrict__ bias,
                                                  const float* __restrict__ biasSk,
                                                  void* __restrict__ outp) {
    const int node = blockIdx.x * 4 + (threadIdx.x >> 6);
    const int t = threadIdx.x & 63;
    const int g = t & 15;                    // col group
    const int h = g >> 2;                    // head
    const int eo = t >> 4;                   // edge slot
    const int start = off[node];
    const int end = off[node + 1];
    const float adH = alD[(size_t)node * 4 + h];
    const uint4* __restrict__ hw16 = reinterpret_cast<const uint4*>(hwB);

    float a0 = 0.f, a1 = 0.f, a2 = 0.f, a3 = 0.f;
    float a4 = 0.f, a5 = 0.f, a6 = 0.f, a7 = 0.f;
    float sA = 0.f;

    for (int j = start; j < end; j += 4) {
        int ej = j + eo;
        bool valid = ej < end;
        int s = csr[valid ? ej : end - 1];
        float al = alS[(size_t)s * 4 + h];
        float ex = valid ? __expf(lrelu(al + adH)) : 0.f;
        uint4 u = hw16[(size_t)s * 16 + g];
        sA += ex;
        a0 += ex * bflo(u.x); a1 += ex * bfhi(u.x);
        a2 += ex * bflo(u.y); a3 += ex * bfhi(u.y);
        a4 += ex * bflo(u.z); a5 += ex * bfhi(u.z);
        a6 += ex * bflo(u.w); a7 += ex * bfhi(u.w);
    }
    // combine the 4 edge slots (lanes t, t^16, t^32, t^48)
    #pragma unroll
    for (int o = 16; o <= 32; o <<= 1) {
        sA += __shfl_xor(sA, o, 64);
        a0 += __shfl_xor(a0, o, 64); a1 += __shfl_xor(a1, o, 64);
        a2 += __shfl_xor(a2, o, 64); a3 += __shfl_xor(a3, o, 64);
        a4 += __shfl_xor(a4, o, 64); a5 += __shfl_xor(a5, o, 64);
        a6 += __shfl_xor(a6, o, 64); a7 += __shfl_xor(a7, o, 64);
    }
    const float inv = 1.f / (sA + 1e-16f);

    if (FINAL == 0) {
        if (t < 16) {
            int cb = g * 8;
            float4 sk0 = *reinterpret_cast<const float4*>(hsk + (size_t)node * 128 + cb);
            float4 sk1 = *reinterpret_cast<const float4*>(hsk + (size_t)node * 128 + cb + 4);
            float v[8] = {a0 * inv, a1 * inv, a2 * inv, a3 * inv,
                          a4 * inv, a5 * inv, a6 * inv, a7 * inv};
            float skv[8] = {sk0.x, sk0.y, sk0.z, sk0.w, sk1.x, sk1.y, sk1.z, sk1.w};
            uint_t pk[4];
            #pragma unroll
            for (int k = 0; k < 8; ++k) {
                float w = v[k] + bias[cb + k] + biasSk[cb + k] + skv[k];
                w = w > 0.f ? w : expm1f(w);
                if (k & 1) pk[k >> 1] |= ((uint_t)f2bf(w)) << 16;
                else       pk[k >> 1] = (uint_t)f2bf(w);
            }
            uint4 o4 = make_uint4(pk[0], pk[1], pk[2], pk[3]);
            reinterpret_cast<uint4*>(outp)[(size_t)node * 16 + g] = o4;
        }
    } else {
        // normalize per-head, then sum over heads (lanes g, g^4, g^8, g^12)
        float v[8] = {a0 * inv, a1 * inv, a2 * inv, a3 * inv,
                      a4 * inv, a5 * inv, a6 * inv, a7 * inv};
        #pragma unroll
        for (int o = 4; o <= 8; o <<= 1)
            #pragma unroll
            for (int k = 0; k < 8; ++k) v[k] += __shfl_xor(v[k], o, 64);
        if (t < 4) {
            int cb = t * 8;
            float ss = 0.f;
            #pragma unroll
            for (int k = 0; k < 8; ++k) {
                v[k] = v[k] * 0.25f + bias[cb + k] + biasSk[cb + k]
                       + hsk[(size_t)node * 32 + cb + k];
                ss += v[k] * v[k];
            }
            ss += __shfl_xor(ss, 1, 64);
            ss += __shfl_xor(ss, 2, 64);
            float r = 1.f / fmaxf(sqrtf(ss), 1e-12f);
            float* out = reinterpret_cast<float*>(outp);
            float4 w0 = make_float4(v[0] * r, v[1] * r, v[2] * r, v[3] * r);
            float4 w1 = make_float4(v[4] * r, v[5] * r, v[6] * r, v[7] * r);
            *reinterpret_cast<float4*>(out + (size_t)node * 32 + cb) = w0;
            *reinterpret_cast<float4*>(out + (size_t)node * 32 + cb + 4) = w1;
        }
    }
}

// ---------------------------------------------------------------------------
// launch
// ---------------------------------------------------------------------------
extern "C" void kernel_launch(void* const* d_in, const int* in_sizes, int n_in,
                              void* d_out, int out_size, void* d_ws, size_t ws_size,
                              hipStream_t stream) {
    const float* x   = (const float*)d_in[0];
    const int*   ei  = (const int*)d_in[1];
    const float* W0  = (const float*)d_in[2];
    const float* aS0 = (const float*)d_in[3];
    const float* aD0 = (const float*)d_in[4];
    const float* b0  = (const float*)d_in[5];
    const float* Ws0 = (const float*)d_in[6];
    const float* bs0 = (const float*)d_in[7];
    const float* W1  = (const float*)d_in[8];
    const float* aS1 = (const float*)d_in[9];
    const float* aD1 = (const float*)d_in[10];
    const float* b1  = (const float*)d_in[11];
    const float* Ws1 = (const float*)d_in[12];
    const float* bs1 = (const float*)d_in[13];
    const float* W2  = (const float*)d_in[14];
    const float* aS2 = (const float*)d_in[15];
    const float* aD2 = (const float*)d_in[16];
    const float* b2  = (const float*)d_in[17];
    const float* Ws2 = (const float*)d_in[18];
    const float* bs2 = (const float*)d_in[19];
    float* out = (float*)d_out;

    char* p = (char*)d_ws;
    auto alloc = [&](size_t bytes) -> char* {
        char* q = p;
        p += (bytes + 255) & ~(size_t)255;
        return q;
    };
    int*      cnt   = (int*)alloc((size_t)NN * 4);
    int*      off   = (int*)alloc((size_t)(NN + 1) * 4);
    int*      csr   = (int*)alloc((size_t)NE * 4);
    int*      bsum  = (int*)alloc((size_t)NB * 4);
    int*      bpre  = (int*)alloc((size_t)NB * 4);
    ushort_t* hwB   = (ushort_t*)alloc((size_t)NN * 128 * 2);
    ushort_t* hbufB = (ushort_t*)alloc((size_t)NN * 128 * 2);
    float*    hsk   = (float*)alloc((size_t)NN * 128 * 4);
    float*    alS   = (float*)alloc((size_t)NN * 4 * 4);
    float*    alD   = (float*)alloc((size_t)NN * 4 * 4);
    ushort_t* Wt0   = (ushort_t*)alloc((size_t)128 * 128 * 2);
    ushort_t* Wts0  = (ushort_t*)alloc((size_t)128 * 128 * 2);
    ushort_t* Wt1   = (ushort_t*)alloc((size_t)128 * 128 * 2);
    ushort_t* Wts1  = (ushort_t*)alloc((size_t)128 * 128 * 2);
    ushort_t* Wt2   = (ushort_t*)alloc((size_t)128 * 128 * 2);
    ushort_t* Wts2  = (ushort_t*)alloc((size_t)32 * 128 * 2);

    const int EB = (NE + 255) / 256;
    const dim3 gg((NN + 127) / 128, 2);   // (391, 2)
    const int AGGB = NN / 4;

    // weight conversions (one kernel)
    wcvt_all<<<336, 256, 0, stream>>>(W0, Ws0, W1, Ws1, W2, Ws2,
                                      Wt0, Wts0, Wt1, Wts1, Wt2, Wts2);

    // CSR build
    zero_kernel<<<(NN + 255) / 256, 256, 0, stream>>>(cnt, NN);
    count_kernel<<<EB, 256, 0, stream>>>(ei, cnt, NE);
    psum_kernel<<<NB, 256, 0, stream>>>(cnt, bsum);
    bscan_kernel<<<1, 256, 0, stream>>>(bsum, bpre);
    scan3_kernel<<<NB, 256, 0, stream>>>(cnt, bpre, off);
    fill_kernel<<<EB, 256, 0, stream>>>(ei, off, cnt, csr, NE);

    // ---- layer 0 (A = x fp32, converted inline)
    gemm_fused<1><<<gg, 256, 0, stream>>>(x, Wt0, hwB, Wts0, hsk,
                                          aS0, aD0, alS, alD, NN, 128);
    agg_kernel<0><<<AGGB, 256, 0, stream>>>(off, csr, alS, alD, hwB, hsk, b0, bs0, hbufB);

    // ---- layer 1 (A = hbufB bf16)
    gemm_fused<0><<<gg, 256, 0, stream>>>(hbufB, Wt1, hwB, Wts1, hsk,
                                          aS1, aD1, alS, alD, NN, 128);
    agg_kernel<0><<<AGGB, 256, 0, stream>>>(off, csr, alS, alD, hwB, hsk, b1, bs1, hbufB);

    // ---- layer 2 (skip GEMM N2=32; head-mean + L2 normalize)
    gemm_fused<0><<<gg, 256, 0, stream>>>(hbufB, Wt2, hwB, Wts2, hsk,
                                          aS2, aD2, alS, alD, NN, 32);
    agg_kernel<1><<<AGGB, 256, 0, stream>>>(off, csr, alS, alD, hwB, hsk, b2, bs2, out);
}

// Round 6
// 420.059 us; speedup vs baseline: 1.6461x; 1.0660x over previous
//
#include <hip/hip_runtime.h>
#include <hip/hip_bf16.h>
#include <cstdint>
#include <cstddef>

#define NN 50000
#define NE 800000
#define NB 196   // ceil(NN/256)

typedef __attribute__((ext_vector_type(8))) short short8v;
typedef __attribute__((ext_vector_type(4))) float f32x4;
typedef unsigned short ushort_t;
typedef unsigned int uint_t;

// ---------------------------------------------------------------------------
// helpers
// ---------------------------------------------------------------------------
__device__ __forceinline__ float lrelu(float v) {
    return v > 0.f ? v : 0.2f * v;
}
__device__ __forceinline__ ushort_t f2bf(float f) {
    __hip_bfloat16 h = __float2bfloat16(f);
    return *reinterpret_cast<ushort_t*>(&h);
}
__device__ __forceinline__ float bflo(uint_t u) { return __uint_as_float(u << 16); }
__device__ __forceinline__ float bfhi(uint_t u) { return __uint_as_float(u & 0xffff0000u); }

// ---------------------------------------------------------------------------
// all weight conversions in ONE kernel: W [128][N] fp32 -> Wt bf16 [N][128]
// ---------------------------------------------------------------------------
__global__ __launch_bounds__(256) void wcvt_all(
    const float* __restrict__ W0, const float* __restrict__ Ws0,
    const float* __restrict__ W1, const float* __restrict__ Ws1,
    const float* __restrict__ W2, const float* __restrict__ Ws2,
    ushort_t* __restrict__ T0, ushort_t* __restrict__ Ts0,
    ushort_t* __restrict__ T1, ushort_t* __restrict__ Ts1,
    ushort_t* __restrict__ T2, ushort_t* __restrict__ Ts2) {
    int idx = blockIdx.x * 256 + threadIdx.x;
    if (idx < 81920) {
        int m = idx >> 14;          // which 128x128 matrix
        int i = idx & 16383;
        const float* src; ushort_t* dst;
        switch (m) {
            case 0: src = W0;  dst = T0;  break;
            case 1: src = Ws0; dst = Ts0; break;
            case 2: src = W1;  dst = T1;  break;
            case 3: src = Ws1; dst = Ts1; break;
            default: src = W2; dst = T2;  break;
        }
        int k = i >> 7, n = i & 127;
        dst[n * 128 + k] = f2bf(src[i]);
    } else {
        int i = idx - 81920;        // 4096 elems of Ws2 [128][32]
        int k = i >> 5, n = i & 31;
        Ts2[n * 128 + k] = f2bf(Ws2[i]);
    }
}

// ---------------------------------------------------------------------------
// CSR build: memset -> count -> 3-kernel parallel scan -> fill
// ---------------------------------------------------------------------------
__global__ void count_kernel(const int* __restrict__ ei, int* __restrict__ cnt, int E) {
    int e = blockIdx.x * blockDim.x + threadIdx.x;
    if (e < E) atomicAdd(&cnt[ei[E + e]], 1);
}

__global__ __launch_bounds__(256) void psum_kernel(const int* __restrict__ cnt,
                                                   int* __restrict__ bsum) {
    int i = blockIdx.x * 256 + threadIdx.x;
    int v = (i < NN) ? cnt[i] : 0;
    #pragma unroll
    for (int o = 1; o < 64; o <<= 1) v += __shfl_xor(v, o, 64);
    __shared__ int ws[4];
    if ((threadIdx.x & 63) == 0) ws[threadIdx.x >> 6] = v;
    __syncthreads();
    if (threadIdx.x == 0) bsum[blockIdx.x] = ws[0] + ws[1] + ws[2] + ws[3];
}

__global__ __launch_bounds__(256) void bscan_kernel(const int* __restrict__ bsum,
                                                    int* __restrict__ bpre) {
    int t = threadIdx.x;
    int lane = t & 63, w = t >> 6;
    int v = (t < NB) ? bsum[t] : 0;
    int x = v;
    #pragma unroll
    for (int o = 1; o < 64; o <<= 1) {
        int y = __shfl_up(x, o, 64);
        if (lane >= o) x += y;
    }
    __shared__ int ws[4];
    if (lane == 63) ws[w] = x;
    __syncthreads();
    if (t == 0) {
        int s = 0;
        #pragma unroll
        for (int q = 0; q < 4; ++q) { int tmp = ws[q]; ws[q] = s; s += tmp; }
    }
    __syncthreads();
    if (t < NB) bpre[t] = (x - v) + ws[w];
}

__global__ __launch_bounds__(256) void scan3_kernel(int* __restrict__ cnt,
                                                    const int* __restrict__ bpre,
                                                    int* __restrict__ off) {
    int b = blockIdx.x, t = threadIdx.x;
    int i = b * 256 + t;
    int lane = t & 63, w = t >> 6;
    int v = (i < NN) ? cnt[i] : 0;
    if (i < NN) cnt[i] = 0;                  // reuse as fill cursor
    int x = v;
    #pragma unroll
    for (int o = 1; o < 64; o <<= 1) {
        int y = __shfl_up(x, o, 64);
        if (lane >= o) x += y;
    }
    __shared__ int ws[4];
    if (lane == 63) ws[w] = x;
    __syncthreads();
    if (t == 0) {
        int s = 0;
        #pragma unroll
        for (int q = 0; q < 4; ++q) { int tmp = ws[q]; ws[q] = s; s += tmp; }
    }
    __syncthreads();
    int incl = x + ws[w];
    if (i < NN) off[i + 1] = bpre[b] + incl;
    if (i == 0) off[0] = 0;
}

__global__ void fill_kernel(const int* __restrict__ ei, const int* __restrict__ off,
                            int* __restrict__ cursor, int* __restrict__ csr, int E) {
    int e = blockIdx.x * blockDim.x + threadIdx.x;
    if (e < E) {
        int s = ei[e];
        int d = ei[E + e];
        int pos = off[d] + atomicAdd(&cursor[d], 1);
        csr[pos] = s;
    }
}

// ---------------------------------------------------------------------------
// LDS-staged MFMA GEMM + fused attention-logit epilogue. K=128 fixed.
// A: fp32 [M][128] (AFP32=1) or bf16 [M][128] (AFP32=0).
// y=0: C1 = A@B1^T -> bf16 [M][128], plus alS/alD = (A@B1)·aS/aD per head.
// y=1: C2 = A@B2^T -> fp32 [M][N2] (N2 = 128 or 32).
// LDS XOR swizzle bits 4..6 by row: stride-256B frag ds_read_b128 2-way (free).
// ---------------------------------------------------------------------------
template <int AFP32>
__global__ __launch_bounds__(256) void gemm_fused(const void* __restrict__ Ap,
                                                  const ushort_t* __restrict__ Bt1,
                                                  ushort_t* __restrict__ C1,
                                                  const ushort_t* __restrict__ Bt2,
                                                  float* __restrict__ C2,
                                                  const float* __restrict__ aS,
                                                  const float* __restrict__ aD,
                                                  float* __restrict__ alS,
                                                  float* __restrict__ alD,
                                                  int M, int N2) {
    __shared__ ushort_t As[128 * 128];   // 32KB swizzled
    __shared__ ushort_t Bs[128 * 128];   // 32KB swizzled
    const int tid = threadIdx.x;
    const int wave = tid >> 6;
    const int lane = tid & 63;
    const int l15 = lane & 15;
    const int kg = lane >> 4;            // 0..3
    const bool second = (blockIdx.y == 1);
    const int m0 = blockIdx.x * 128;
    const int Ncols = second ? N2 : 128;

    // ---- stage A (coalesced, swizzled write)
    if (AFP32) {
        const float* A = (const float*)Ap;
        const int c = tid & 31;          // 8B dest chunk / 16B src chunk
        #pragma unroll
        for (int q = 0; q < 16; ++q) {
            int row = (tid >> 5) + q * 8;
            int sr = m0 + row; sr = sr < M ? sr : M - 1;
            float4 v = *reinterpret_cast<const float4*>(A + (size_t)sr * 128 + c * 4);
            uint_t u0 = (uint_t)f2bf(v.x) | ((uint_t)f2bf(v.y) << 16);
            uint_t u1 = (uint_t)f2bf(v.z) | ((uint_t)f2bf(v.w) << 16);
            int bo = row * 256 + ((c * 8) ^ ((row & 7) << 4));
            *reinterpret_cast<uint2*>(reinterpret_cast<char*>(As) + bo) = make_uint2(u0, u1);
        }
    } else {
        const ushort_t* A = (const ushort_t*)Ap;
        const int c = tid & 15;          // 16B chunk
        #pragma unroll
        for (int q = 0; q < 8; ++q) {
            int row = (tid >> 4) + q * 16;
            int sr = m0 + row; sr = sr < M ? sr : M - 1;
            uint4 v = *reinterpret_cast<const uint4*>(A + (size_t)sr * 128 + c * 8);
            int bo = row * 256 + ((c * 16) ^ ((row & 7) << 4));
            *reinterpret_cast<uint4*>(reinterpret_cast<char*>(As) + bo) = v;
        }
    }
    // ---- stage B (rows of Bt = output cols)
    {
        const ushort_t* Bt = second ? Bt2 : Bt1;
        const int c = tid & 15;
        for (int row = tid >> 4; row < Ncols; row += 16) {
            uint4 v = *reinterpret_cast<const uint4*>(Bt + (size_t)row * 128 + c * 8);
            int bo = row * 256 + ((c * 16) ^ ((row & 7) << 4));
            *reinterpret_cast<uint4*>(reinterpret_cast<char*>(Bs) + bo) = v;
        }
    }
    __syncthreads();

    const int r0 = (wave & 1) * 64;      // tile-local row base for this wave
    const int c0 = (wave >> 1) * 64;     // col base
    if (c0 >= Ncols) return;
    const int nF = (Ncols - c0) >= 64 ? 4 : ((Ncols - c0) >> 4);

    f32x4 acc[4][4];
    #pragma unroll
    for (int i = 0; i < 4; ++i)
        #pragma unroll
        for (int j = 0; j < 4; ++j) acc[i][j] = (f32x4){0.f, 0.f, 0.f, 0.f};

    #pragma unroll
    for (int ks = 0; ks < 4; ++ks) {
        const int kb = kg * 16 + ks * 64;   // frag k byte offset
        short8v a[4], b[4];
        #pragma unroll
        for (int fm = 0; fm < 4; ++fm) {
            int row = r0 + fm * 16 + l15;
            int bo = row * 256 + (kb ^ ((row & 7) << 4));
            a[fm] = *reinterpret_cast<const short8v*>(reinterpret_cast<const char*>(As) + bo);
        }
        #pragma unroll
        for (int fn = 0; fn < 4; ++fn) {
            if (fn < nF) {
                int row = c0 + fn * 16 + l15;
                int bo = row * 256 + (kb ^ ((row & 7) << 4));
                b[fn] = *reinterpret_cast<const short8v*>(reinterpret_cast<const char*>(Bs) + bo);
            }
        }
        #pragma unroll
        for (int fm = 0; fm < 4; ++fm)
            #pragma unroll
            for (int fn = 0; fn < 4; ++fn)
                if (fn < nF)
                    acc[fm][fn] = __builtin_amdgcn_mfma_f32_16x16x32_bf16(
                        a[fm], b[fn], acc[fm][fn], 0, 0, 0);
    }

    // ---- C write.  C/D frag: col = l15, row = kg*4 + reg  [m89/m91]
    #pragma unroll
    for (int fm = 0; fm < 4; ++fm) {
        #pragma unroll
        for (int r = 0; r < 4; ++r) {
            int row = m0 + r0 + fm * 16 + kg * 4 + r;
            if (row < M) {
                #pragma unroll
                for (int fn = 0; fn < 4; ++fn) {
                    if (fn < nF) {
                        int col = c0 + fn * 16 + l15;
                        float v = acc[fm][fn][r];
                        if (second) C2[(size_t)row * Ncols + col] = v;
                        else        C1[(size_t)row * 128 + col] = f2bf(v);
                    }
                }
            }
        }
    }

    // ---- fused attention-logit epilogue (y=0 only): alS/alD from fp32 acc
    if (!second) {
        float aSv[4], aDv[4];
        #pragma unroll
        for (int fn = 0; fn < 4; ++fn) {
            aSv[fn] = aS[c0 + fn * 16 + l15];
            aDv[fn] = aD[c0 + fn * 16 + l15];
        }
        const int hb = c0 >> 5;          // head base: 0 or 2
        #pragma unroll
        for (int fm = 0; fm < 4; ++fm) {
            #pragma unroll
            for (int r = 0; r < 4; ++r) {
                float s0 = acc[fm][0][r] * aSv[0] + acc[fm][1][r] * aSv[1];
                float s1 = acc[fm][2][r] * aSv[2] + acc[fm][3][r] * aSv[3];
                float d0 = acc[fm][0][r] * aDv[0] + acc[fm][1][r] * aDv[1];
                float d1 = acc[fm][2][r] * aDv[2] + acc[fm][3][r] * aDv[3];
                #pragma unroll
                for (int o = 1; o < 16; o <<= 1) {
                    s0 += __shfl_xor(s0, o, 64);
                    s1 += __shfl_xor(s1, o, 64);
                    d0 += __shfl_xor(d0, o, 64);
                    d1 += __shfl_xor(d1, o, 64);
                }
                if (l15 == 0) {
                    int row = m0 + r0 + fm * 16 + kg * 4 + r;
                    if (row < M) {
                        *reinterpret_cast<float2*>(alS + (size_t)row * 4 + hb) = make_float2(s0, s1);
                        *reinterpret_cast<float2*>(alD + (size_t)row * 4 + hb) = make_float2(d0, d1);
                    }
                }
            }
        }
    }
}

// ---------------------------------------------------------------------------
// softmax + aggregation v3 — break the gather chain.
// One wave per node (4 nodes / 256-thr block). Per 64-edge chunk:
//   (a) coalesced csr load -> sv in registers (whole wave)
//   (b) lane t computes exp(lrelu(alS[sv]+alD)) for its edge, all 4 heads
//       (one 16B gather + 4 exps), parks float4 in LDS (4KB/block)
//   (c) inner loop, 4 edges/iter: s via __shfl (bpermute, no mem latency),
//       ex via conflict-free LDS broadcast, ONE VMEM gather (hw row 16B/lane).
// FINAL=0: out bf16 [N][128] (+bias+skip fp32, ELU).
// FINAL=1: head-mean, +skip, L2-normalize, out fp32 [N][32].
// ---------------------------------------------------------------------------
template <int FINAL>
__global__ __launch_bounds__(256) void agg_kernel(const int* __restrict__ off,
                                                  const int* __restrict__ csr,
                                                  const float* __restrict__ alS,
                                                  const float* __restrict__ alD,
                                                  const ushort_t* __restrict__ hwB,
                                                  const float* __restrict__ hsk,
                                                  const float* __restrict__ bias,
                                                  const float* __restrict__ biasSk,
                                                  void* __restrict__ outp) {
    __shared__ float ex_lds[4][64][4];       // 4KB
    const int w = threadIdx.x >> 6;
    const int node = blockIdx.x * 4 + w;
    const int t = threadIdx.x & 63;
    const int g = t & 15;                    // col group (16B of hw row)
    const int h = g >> 2;                    // head
    const int eo = t >> 4;                   // edge slot
    const int start = off[node];
    const int deg = off[node + 1] - start;
    const float4 ad4 = *reinterpret_cast<const float4*>(alD + (size_t)node * 4);
    const uint4* __restrict__ hw16 = reinterpret_cast<const uint4*>(hwB);

    float a0 = 0.f, a1 = 0.f, a2 = 0.f, a3 = 0.f;
    float a4 = 0.f, a5 = 0.f, a6 = 0.f, a7 = 0.f;
    float sA = 0.f;

    for (int cb = 0; cb < deg; cb += 64) {
        const int ce = min(64, deg - cb);
        // (a)+(b): chunk preload + softmax numerators
        const int li = t < ce ? t : ce - 1;
        const int sv = csr[start + cb + li];
        {
            float4 al4 = *reinterpret_cast<const float4*>(alS + (size_t)sv * 4);
            bool lv = t < ce;
            float e0 = lv ? __expf(lrelu(al4.x + ad4.x)) : 0.f;
            float e1 = lv ? __expf(lrelu(al4.y + ad4.y)) : 0.f;
            float e2 = lv ? __expf(lrelu(al4.z + ad4.z)) : 0.f;
            float e3 = lv ? __expf(lrelu(al4.w + ad4.w)) : 0.f;
            *reinterpret_cast<float4*>(&ex_lds[w][t][0]) = make_float4(e0, e1, e2, e3);
        }
        // wave-private LDS: compiler inserts lgkmcnt wait; no barrier needed
        // (c): accumulate, 4 edges per iteration, one VMEM gather each
        for (int jr = 0; jr < ce; jr += 4) {
            int ej = jr + eo;
            int ejc = ej < ce ? ej : 0;
            int s = __shfl(sv, ejc, 64);
            float ex = ex_lds[w][ejc][h];
            ex = (ej < ce) ? ex : 0.f;
            uint4 u = hw16[(size_t)s * 16 + g];
            sA += ex;
            a0 += ex * bflo(u.x); a1 += ex * bfhi(u.x);
            a2 += ex * bflo(u.y); a3 += ex * bfhi(u.y);
            a4 += ex * bflo(u.z); a5 += ex * bfhi(u.z);
            a6 += ex * bflo(u.w); a7 += ex * bfhi(u.w);
        }
    }

    // combine the 4 edge slots (lanes t, t^16, t^32, t^48)
    #pragma unroll
    for (int o = 16; o <= 32; o <<= 1) {
        sA += __shfl_xor(sA, o, 64);
        a0 += __shfl_xor(a0, o, 64); a1 += __shfl_xor(a1, o, 64);
        a2 += __shfl_xor(a2, o, 64); a3 += __shfl_xor(a3, o, 64);
        a4 += __shfl_xor(a4, o, 64); a5 += __shfl_xor(a5, o, 64);
        a6 += __shfl_xor(a6, o, 64); a7 += __shfl_xor(a7, o, 64);
    }
    const float inv = 1.f / (sA + 1e-16f);

    if (FINAL == 0) {
        if (t < 16) {
            int cb = g * 8;
            float4 sk0 = *reinterpret_cast<const float4*>(hsk + (size_t)node * 128 + cb);
            float4 sk1 = *reinterpret_cast<const float4*>(hsk + (size_t)node * 128 + cb + 4);
            float v[8] = {a0 * inv, a1 * inv, a2 * inv, a3 * inv,
                          a4 * inv, a5 * inv, a6 * inv, a7 * inv};
            float skv[8] = {sk0.x, sk0.y, sk0.z, sk0.w, sk1.x, sk1.y, sk1.z, sk1.w};
            uint_t pk[4];
            #pragma unroll
            for (int k = 0; k < 8; ++k) {
                float wv = v[k] + bias[cb + k] + biasSk[cb + k] + skv[k];
                wv = wv > 0.f ? wv : expm1f(wv);
                if (k & 1) pk[k >> 1] |= ((uint_t)f2bf(wv)) << 16;
                else       pk[k >> 1] = (uint_t)f2bf(wv);
            }
            uint4 o4 = make_uint4(pk[0], pk[1], pk[2], pk[3]);
            reinterpret_cast<uint4*>(outp)[(size_t)node * 16 + g] = o4;
        }
    } else {
        // per-head weighted means, then sum over heads (lanes g, g^4, g^8, g^12)
        float v[8] = {a0 * inv, a1 * inv, a2 * inv, a3 * inv,
                      a4 * inv, a5 * inv, a6 * inv, a7 * inv};
        #pragma unroll
        for (int o = 4; o <= 8; o <<= 1)
            #pragma unroll
            for (int k = 0; k < 8; ++k) v[k] += __shfl_xor(v[k], o, 64);
        if (t < 4) {
            int cb = t * 8;
            float ss = 0.f;
            #pragma unroll
            for (int k = 0; k < 8; ++k) {
                v[k] = v[k] * 0.25f + bias[cb + k] + biasSk[cb + k]
                       + hsk[(size_t)node * 32 + cb + k];
                ss += v[k] * v[k];
            }
            ss += __shfl_xor(ss, 1, 64);
            ss += __shfl_xor(ss, 2, 64);
            float r = 1.f / fmaxf(sqrtf(ss), 1e-12f);
            float* out = reinterpret_cast<float*>(outp);
            float4 w0 = make_float4(v[0] * r, v[1] * r, v[2] * r, v[3] * r);
            float4 w1 = make_float4(v[4] * r, v[5] * r, v[6] * r, v[7] * r);
            *reinterpret_cast<float4*>(out + (size_t)node * 32 + cb) = w0;
            *reinterpret_cast<float4*>(out + (size_t)node * 32 + cb + 4) = w1;
        }
    }
}

// ---------------------------------------------------------------------------
// launch
// ---------------------------------------------------------------------------
extern "C" void kernel_launch(void* const* d_in, const int* in_sizes, int n_in,
                              void* d_out, int out_size, void* d_ws, size_t ws_size,
                              hipStream_t stream) {
    const float* x   = (const float*)d_in[0];
    const int*   ei  = (const int*)d_in[1];
    const float* W0  = (const float*)d_in[2];
    const float* aS0 = (const float*)d_in[3];
    const float* aD0 = (const float*)d_in[4];
    const float* b0  = (const float*)d_in[5];
    const float* Ws0 = (const float*)d_in[6];
    const float* bs0 = (const float*)d_in[7];
    const float* W1  = (const float*)d_in[8];
    const float* aS1 = (const float*)d_in[9];
    const float* aD1 = (const float*)d_in[10];
    const float* b1  = (const float*)d_in[11];
    const float* Ws1 = (const float*)d_in[12];
    const float* bs1 = (const float*)d_in[13];
    const float* W2  = (const float*)d_in[14];
    const float* aS2 = (const float*)d_in[15];
    const float* aD2 = (const float*)d_in[16];
    const float* b2  = (const float*)d_in[17];
    const float* Ws2 = (const float*)d_in[18];
    const float* bs2 = (const float*)d_in[19];
    float* out = (float*)d_out;

    char* p = (char*)d_ws;
    auto alloc = [&](size_t bytes) -> char* {
        char* q = p;
        p += (bytes + 255) & ~(size_t)255;
        return q;
    };
    int*      cnt   = (int*)alloc((size_t)NN * 4);
    int*      off   = (int*)alloc((size_t)(NN + 1) * 4);
    int*      csr   = (int*)alloc((size_t)NE * 4);
    int*      bsum  = (int*)alloc((size_t)NB * 4);
    int*      bpre  = (int*)alloc((size_t)NB * 4);
    ushort_t* hwB   = (ushort_t*)alloc((size_t)NN * 128 * 2);
    ushort_t* hbufB = (ushort_t*)alloc((size_t)NN * 128 * 2);
    float*    hsk   = (float*)alloc((size_t)NN * 128 * 4);
    float*    alS   = (float*)alloc((size_t)NN * 4 * 4);
    float*    alD   = (float*)alloc((size_t)NN * 4 * 4);
    ushort_t* Wt0   = (ushort_t*)alloc((size_t)128 * 128 * 2);
    ushort_t* Wts0  = (ushort_t*)alloc((size_t)128 * 128 * 2);
    ushort_t* Wt1   = (ushort_t*)alloc((size_t)128 * 128 * 2);
    ushort_t* Wts1  = (ushort_t*)alloc((size_t)128 * 128 * 2);
    ushort_t* Wt2   = (ushort_t*)alloc((size_t)128 * 128 * 2);
    ushort_t* Wts2  = (ushort_t*)alloc((size_t)32 * 128 * 2);

    const int EB = (NE + 255) / 256;
    const dim3 gg((NN + 127) / 128, 2);   // (391, 2)
    const int AGGB = NN / 4;

    // weight conversions (one kernel)
    wcvt_all<<<336, 256, 0, stream>>>(W0, Ws0, W1, Ws1, W2, Ws2,
                                      Wt0, Wts0, Wt1, Wts1, Wt2, Wts2);

    // CSR build
    hipMemsetAsync(cnt, 0, (size_t)NN * 4, stream);
    count_kernel<<<EB, 256, 0, stream>>>(ei, cnt, NE);
    psum_kernel<<<NB, 256, 0, stream>>>(cnt, bsum);
    bscan_kernel<<<1, 256, 0, stream>>>(bsum, bpre);
    scan3_kernel<<<NB, 256, 0, stream>>>(cnt, bpre, off);
    fill_kernel<<<EB, 256, 0, stream>>>(ei, off, cnt, csr, NE);

    // ---- layer 0 (A = x fp32, converted inline)
    gemm_fused<1><<<gg, 256, 0, stream>>>(x, Wt0, hwB, Wts0, hsk,
                                          aS0, aD0, alS, alD, NN, 128);
    agg_kernel<0><<<AGGB, 256, 0, stream>>>(off, csr, alS, alD, hwB, hsk, b0, bs0, hbufB);

    // ---- layer 1 (A = hbufB bf16)
    gemm_fused<0><<<gg, 256, 0, stream>>>(hbufB, Wt1, hwB, Wts1, hsk,
                                          aS1, aD1, alS, alD, NN, 128);
    agg_kernel<0><<<AGGB, 256, 0, stream>>>(off, csr, alS, alD, hwB, hsk, b1, bs1, hbufB);

    // ---- layer 2 (skip GEMM N2=32; head-mean + L2 normalize)
    gemm_fused<0><<<gg, 256, 0, stream>>>(hbufB, Wt2, hwB, Wts2, hsk,
                                          aS2, aD2, alS, alD, NN, 32);
    agg_kernel<1><<<AGGB, 256, 0, stream>>>(off, csr, alS, alD, hwB, hsk, b2, bs2, out);
}

// Round 7
// 390.210 us; speedup vs baseline: 1.7721x; 1.0765x over previous
//
#include <hip/hip_runtime.h>
#include <hip/hip_bf16.h>
#include <cstdint>
#include <cstddef>

#define NN 50000
#define NE 800000
#define NB 196   // ceil(NN/256)

typedef __attribute__((ext_vector_type(8))) short short8v;
typedef __attribute__((ext_vector_type(4))) float f32x4;
typedef unsigned short ushort_t;
typedef unsigned int uint_t;

// ---------------------------------------------------------------------------
// helpers
// ---------------------------------------------------------------------------
__device__ __forceinline__ float lrelu(float v) {
    return v > 0.f ? v : 0.2f * v;
}
__device__ __forceinline__ ushort_t f2bf(float f) {
    __hip_bfloat16 h = __float2bfloat16(f);
    return *reinterpret_cast<ushort_t*>(&h);
}
__device__ __forceinline__ float bflo(uint_t u) { return __uint_as_float(u << 16); }
__device__ __forceinline__ float bfhi(uint_t u) { return __uint_as_float(u & 0xffff0000u); }

// ---------------------------------------------------------------------------
// all weight conversions in ONE kernel: W [128][N] fp32 -> Wt bf16 [N][128]
// also zeroes cnt (folds the memset dispatch)
// ---------------------------------------------------------------------------
__global__ __launch_bounds__(256) void wcvt_all(
    const float* __restrict__ W0, const float* __restrict__ Ws0,
    const float* __restrict__ W1, const float* __restrict__ Ws1,
    const float* __restrict__ W2, const float* __restrict__ Ws2,
    ushort_t* __restrict__ T0, ushort_t* __restrict__ Ts0,
    ushort_t* __restrict__ T1, ushort_t* __restrict__ Ts1,
    ushort_t* __restrict__ T2, ushort_t* __restrict__ Ts2,
    int* __restrict__ cnt) {
    int idx = blockIdx.x * 256 + threadIdx.x;
    if (idx < NN) cnt[idx] = 0;
    if (idx < 81920) {
        int m = idx >> 14;          // which 128x128 matrix
        int i = idx & 16383;
        const float* src; ushort_t* dst;
        switch (m) {
            case 0: src = W0;  dst = T0;  break;
            case 1: src = Ws0; dst = Ts0; break;
            case 2: src = W1;  dst = T1;  break;
            case 3: src = Ws1; dst = Ts1; break;
            default: src = W2; dst = T2;  break;
        }
        int k = i >> 7, n = i & 127;
        dst[n * 128 + k] = f2bf(src[i]);
    } else {
        int i = idx - 81920;        // 4096 elems of Ws2 [128][32]
        int k = i >> 5, n = i & 31;
        Ts2[n * 128 + k] = f2bf(Ws2[i]);
    }
}

// ---------------------------------------------------------------------------
// CSR build: count -> 3-kernel parallel scan -> fill
// ---------------------------------------------------------------------------
__global__ void count_kernel(const int* __restrict__ ei, int* __restrict__ cnt, int E) {
    int e = blockIdx.x * blockDim.x + threadIdx.x;
    if (e < E) atomicAdd(&cnt[ei[E + e]], 1);
}

__global__ __launch_bounds__(256) void psum_kernel(const int* __restrict__ cnt,
                                                   int* __restrict__ bsum) {
    int i = blockIdx.x * 256 + threadIdx.x;
    int v = (i < NN) ? cnt[i] : 0;
    #pragma unroll
    for (int o = 1; o < 64; o <<= 1) v += __shfl_xor(v, o, 64);
    __shared__ int ws[4];
    if ((threadIdx.x & 63) == 0) ws[threadIdx.x >> 6] = v;
    __syncthreads();
    if (threadIdx.x == 0) bsum[blockIdx.x] = ws[0] + ws[1] + ws[2] + ws[3];
}

__global__ __launch_bounds__(256) void bscan_kernel(const int* __restrict__ bsum,
                                                    int* __restrict__ bpre) {
    int t = threadIdx.x;
    int lane = t & 63, w = t >> 6;
    int v = (t < NB) ? bsum[t] : 0;
    int x = v;
    #pragma unroll
    for (int o = 1; o < 64; o <<= 1) {
        int y = __shfl_up(x, o, 64);
        if (lane >= o) x += y;
    }
    __shared__ int ws[4];
    if (lane == 63) ws[w] = x;
    __syncthreads();
    if (t == 0) {
        int s = 0;
        #pragma unroll
        for (int q = 0; q < 4; ++q) { int tmp = ws[q]; ws[q] = s; s += tmp; }
    }
    __syncthreads();
    if (t < NB) bpre[t] = (x - v) + ws[w];
}

__global__ __launch_bounds__(256) void scan3_kernel(int* __restrict__ cnt,
                                                    const int* __restrict__ bpre,
                                                    int* __restrict__ off) {
    int b = blockIdx.x, t = threadIdx.x;
    int i = b * 256 + t;
    int lane = t & 63, w = t >> 6;
    int v = (i < NN) ? cnt[i] : 0;
    if (i < NN) cnt[i] = 0;                  // reuse as fill cursor
    int x = v;
    #pragma unroll
    for (int o = 1; o < 64; o <<= 1) {
        int y = __shfl_up(x, o, 64);
        if (lane >= o) x += y;
    }
    __shared__ int ws[4];
    if (lane == 63) ws[w] = x;
    __syncthreads();
    if (t == 0) {
        int s = 0;
        #pragma unroll
        for (int q = 0; q < 4; ++q) { int tmp = ws[q]; ws[q] = s; s += tmp; }
    }
    __syncthreads();
    int incl = x + ws[w];
    if (i < NN) off[i + 1] = bpre[b] + incl;
    if (i == 0) off[0] = 0;
}

__global__ void fill_kernel(const int* __restrict__ ei, const int* __restrict__ off,
                            int* __restrict__ cursor, int* __restrict__ csr, int E) {
    int e = blockIdx.x * blockDim.x + threadIdx.x;
    if (e < E) {
        int s = ei[e];
        int d = ei[E + e];
        int pos = off[d] + atomicAdd(&cursor[d], 1);
        csr[pos] = s;
    }
}

// ---------------------------------------------------------------------------
// LDS-staged MFMA GEMM + fused attention-logit epilogue. K=128 fixed.
// A: fp32 [M][128] (AFP32=1) or bf16 [M][128] (AFP32=0).
// y=0: C1 = A@B1^T -> bf16 [M][128], plus alS/alD = (A@B1)·aS/aD per head.
// y=1: C2 = A@B2^T -> fp32 [M][N2] (N2 = 128 or 32).
// LDS XOR swizzle bits 4..6 by row: stride-256B frag ds_read_b128 2-way (free).
// ---------------------------------------------------------------------------
template <int AFP32>
__global__ __launch_bounds__(256) void gemm_fused(const void* __restrict__ Ap,
                                                  const ushort_t* __restrict__ Bt1,
                                                  ushort_t* __restrict__ C1,
                                                  const ushort_t* __restrict__ Bt2,
                                                  float* __restrict__ C2,
                                                  const float* __restrict__ aS,
                                                  const float* __restrict__ aD,
                                                  float* __restrict__ alS,
                                                  float* __restrict__ alD,
                                                  int M, int N2) {
    __shared__ ushort_t As[128 * 128];   // 32KB swizzled
    __shared__ ushort_t Bs[128 * 128];   // 32KB swizzled
    const int tid = threadIdx.x;
    const int wave = tid >> 6;
    const int lane = tid & 63;
    const int l15 = lane & 15;
    const int kg = lane >> 4;            // 0..3
    const bool second = (blockIdx.y == 1);
    const int m0 = blockIdx.x * 128;
    const int Ncols = second ? N2 : 128;

    // ---- stage A (coalesced, swizzled write)
    if (AFP32) {
        const float* A = (const float*)Ap;
        const int c = tid & 31;          // 8B dest chunk / 16B src chunk
        #pragma unroll
        for (int q = 0; q < 16; ++q) {
            int row = (tid >> 5) + q * 8;
            int sr = m0 + row; sr = sr < M ? sr : M - 1;
            float4 v = *reinterpret_cast<const float4*>(A + (size_t)sr * 128 + c * 4);
            uint_t u0 = (uint_t)f2bf(v.x) | ((uint_t)f2bf(v.y) << 16);
            uint_t u1 = (uint_t)f2bf(v.z) | ((uint_t)f2bf(v.w) << 16);
            int bo = row * 256 + ((c * 8) ^ ((row & 7) << 4));
            *reinterpret_cast<uint2*>(reinterpret_cast<char*>(As) + bo) = make_uint2(u0, u1);
        }
    } else {
        const ushort_t* A = (const ushort_t*)Ap;
        const int c = tid & 15;          // 16B chunk
        #pragma unroll
        for (int q = 0; q < 8; ++q) {
            int row = (tid >> 4) + q * 16;
            int sr = m0 + row; sr = sr < M ? sr : M - 1;
            uint4 v = *reinterpret_cast<const uint4*>(A + (size_t)sr * 128 + c * 8);
            int bo = row * 256 + ((c * 16) ^ ((row & 7) << 4));
            *reinterpret_cast<uint4*>(reinterpret_cast<char*>(As) + bo) = v;
        }
    }
    // ---- stage B (rows of Bt = output cols)
    {
        const ushort_t* Bt = second ? Bt2 : Bt1;
        const int c = tid & 15;
        for (int row = tid >> 4; row < Ncols; row += 16) {
            uint4 v = *reinterpret_cast<const uint4*>(Bt + (size_t)row * 128 + c * 8);
            int bo = row * 256 + ((c * 16) ^ ((row & 7) << 4));
            *reinterpret_cast<uint4*>(reinterpret_cast<char*>(Bs) + bo) = v;
        }
    }
    __syncthreads();

    const int r0 = (wave & 1) * 64;      // tile-local row base for this wave
    const int c0 = (wave >> 1) * 64;     // col base
    if (c0 >= Ncols) return;
    const int nF = (Ncols - c0) >= 64 ? 4 : ((Ncols - c0) >> 4);

    f32x4 acc[4][4];
    #pragma unroll
    for (int i = 0; i < 4; ++i)
        #pragma unroll
        for (int j = 0; j < 4; ++j) acc[i][j] = (f32x4){0.f, 0.f, 0.f, 0.f};

    #pragma unroll
    for (int ks = 0; ks < 4; ++ks) {
        const int kb = kg * 16 + ks * 64;   // frag k byte offset
        short8v a[4], b[4];
        #pragma unroll
        for (int fm = 0; fm < 4; ++fm) {
            int row = r0 + fm * 16 + l15;
            int bo = row * 256 + (kb ^ ((row & 7) << 4));
            a[fm] = *reinterpret_cast<const short8v*>(reinterpret_cast<const char*>(As) + bo);
        }
        #pragma unroll
        for (int fn = 0; fn < 4; ++fn) {
            if (fn < nF) {
                int row = c0 + fn * 16 + l15;
                int bo = row * 256 + (kb ^ ((row & 7) << 4));
                b[fn] = *reinterpret_cast<const short8v*>(reinterpret_cast<const char*>(Bs) + bo);
            }
        }
        #pragma unroll
        for (int fm = 0; fm < 4; ++fm)
            #pragma unroll
            for (int fn = 0; fn < 4; ++fn)
                if (fn < nF)
                    acc[fm][fn] = __builtin_amdgcn_mfma_f32_16x16x32_bf16(
                        a[fm], b[fn], acc[fm][fn], 0, 0, 0);
    }

    // ---- C write.  C/D frag: col = l15, row = kg*4 + reg  [m89/m91]
    #pragma unroll
    for (int fm = 0; fm < 4; ++fm) {
        #pragma unroll
        for (int r = 0; r < 4; ++r) {
            int row = m0 + r0 + fm * 16 + kg * 4 + r;
            if (row < M) {
                #pragma unroll
                for (int fn = 0; fn < 4; ++fn) {
                    if (fn < nF) {
                        int col = c0 + fn * 16 + l15;
                        float v = acc[fm][fn][r];
                        if (second) C2[(size_t)row * Ncols + col] = v;
                        else        C1[(size_t)row * 128 + col] = f2bf(v);
                    }
                }
            }
        }
    }

    // ---- fused attention-logit epilogue (y=0 only): alS/alD from fp32 acc
    if (!second) {
        float aSv[4], aDv[4];
        #pragma unroll
        for (int fn = 0; fn < 4; ++fn) {
            aSv[fn] = aS[c0 + fn * 16 + l15];
            aDv[fn] = aD[c0 + fn * 16 + l15];
        }
        const int hb = c0 >> 5;          // head base: 0 or 2
        #pragma unroll
        for (int fm = 0; fm < 4; ++fm) {
            #pragma unroll
            for (int r = 0; r < 4; ++r) {
                float s0 = acc[fm][0][r] * aSv[0] + acc[fm][1][r] * aSv[1];
                float s1 = acc[fm][2][r] * aSv[2] + acc[fm][3][r] * aSv[3];
                float d0 = acc[fm][0][r] * aDv[0] + acc[fm][1][r] * aDv[1];
                float d1 = acc[fm][2][r] * aDv[2] + acc[fm][3][r] * aDv[3];
                #pragma unroll
                for (int o = 1; o < 16; o <<= 1) {
                    s0 += __shfl_xor(s0, o, 64);
                    s1 += __shfl_xor(s1, o, 64);
                    d0 += __shfl_xor(d0, o, 64);
                    d1 += __shfl_xor(d1, o, 64);
                }
                if (l15 == 0) {
                    int row = m0 + r0 + fm * 16 + kg * 4 + r;
                    if (row < M) {
                        *reinterpret_cast<float2*>(alS + (size_t)row * 4 + hb) = make_float2(s0, s1);
                        *reinterpret_cast<float2*>(alD + (size_t)row * 4 + hb) = make_float2(d0, d1);
                    }
                }
            }
        }
    }
}

// ---------------------------------------------------------------------------
// softmax + aggregation — chunk-preload CSR + LDS-parked softmax numerators.
// One wave per node (4 nodes / 256-thr block).  Inner loop: 4 edges/iter,
// source ids via __shfl, numerators via LDS broadcast, ONE VMEM gather.
// FINAL=0: out bf16 [N][128] (+bias+skip fp32, fast ELU).
// FINAL=1: head-mean, +skip, L2-normalize, out fp32 [N][32].
// ---------------------------------------------------------------------------
template <int FINAL>
__global__ __launch_bounds__(256) void agg_kernel(const int* __restrict__ off,
                                                  const int* __restrict__ csr,
                                                  const float* __restrict__ alS,
                                                  const float* __restrict__ alD,
                                                  const ushort_t* __restrict__ hwB,
                                                  const float* __restrict__ hsk,
                                                  const float* __restrict__ bias,
                                                  const float* __restrict__ biasSk,
                                                  void* __restrict__ outp) {
    __shared__ float ex_lds[4][64][4];       // 4KB
    const int w = threadIdx.x >> 6;
    const int node = blockIdx.x * 4 + w;
    const int t = threadIdx.x & 63;
    const int g = t & 15;                    // col group (16B of hw row)
    const int h = g >> 2;                    // head
    const int eo = t >> 4;                   // edge slot
    const int start = off[node];
    const int deg = off[node + 1] - start;
    const float4 ad4 = *reinterpret_cast<const float4*>(alD + (size_t)node * 4);
    const uint4* __restrict__ hw16 = reinterpret_cast<const uint4*>(hwB);

    float a0 = 0.f, a1 = 0.f, a2 = 0.f, a3 = 0.f;
    float a4 = 0.f, a5 = 0.f, a6 = 0.f, a7 = 0.f;
    float sA = 0.f;

    for (int cb = 0; cb < deg; cb += 64) {
        const int ce = min(64, deg - cb);
        // chunk preload + softmax numerators
        const int li = t < ce ? t : ce - 1;
        const int sv = csr[start + cb + li];
        {
            float4 al4 = *reinterpret_cast<const float4*>(alS + (size_t)sv * 4);
            bool lv = t < ce;
            float e0 = lv ? __expf(lrelu(al4.x + ad4.x)) : 0.f;
            float e1 = lv ? __expf(lrelu(al4.y + ad4.y)) : 0.f;
            float e2 = lv ? __expf(lrelu(al4.z + ad4.z)) : 0.f;
            float e3 = lv ? __expf(lrelu(al4.w + ad4.w)) : 0.f;
            *reinterpret_cast<float4*>(&ex_lds[w][t][0]) = make_float4(e0, e1, e2, e3);
        }
        // wave-private LDS: compiler inserts lgkmcnt wait; no barrier needed
        for (int jr = 0; jr < ce; jr += 4) {
            int ej = jr + eo;
            int ejc = ej < ce ? ej : 0;
            int s = __shfl(sv, ejc, 64);
            float ex = ex_lds[w][ejc][h];
            ex = (ej < ce) ? ex : 0.f;
            uint4 u = hw16[(size_t)s * 16 + g];
            sA += ex;
            a0 += ex * bflo(u.x); a1 += ex * bfhi(u.x);
            a2 += ex * bflo(u.y); a3 += ex * bfhi(u.y);
            a4 += ex * bflo(u.z); a5 += ex * bfhi(u.z);
            a6 += ex * bflo(u.w); a7 += ex * bfhi(u.w);
        }
    }

    // combine the 4 edge slots (lanes t, t^16, t^32, t^48)
    #pragma unroll
    for (int o = 16; o <= 32; o <<= 1) {
        sA += __shfl_xor(sA, o, 64);
        a0 += __shfl_xor(a0, o, 64); a1 += __shfl_xor(a1, o, 64);
        a2 += __shfl_xor(a2, o, 64); a3 += __shfl_xor(a3, o, 64);
        a4 += __shfl_xor(a4, o, 64); a5 += __shfl_xor(a5, o, 64);
        a6 += __shfl_xor(a6, o, 64); a7 += __shfl_xor(a7, o, 64);
    }
    const float inv = 1.f / (sA + 1e-16f);

    if (FINAL == 0) {
        if (t < 16) {
            int cb = g * 8;
            float4 sk0 = *reinterpret_cast<const float4*>(hsk + (size_t)node * 128 + cb);
            float4 sk1 = *reinterpret_cast<const float4*>(hsk + (size_t)node * 128 + cb + 4);
            float4 bi0 = *reinterpret_cast<const float4*>(bias + cb);
            float4 bi1 = *reinterpret_cast<const float4*>(bias + cb + 4);
            float4 bk0 = *reinterpret_cast<const float4*>(biasSk + cb);
            float4 bk1 = *reinterpret_cast<const float4*>(biasSk + cb + 4);
            float v[8] = {a0 * inv, a1 * inv, a2 * inv, a3 * inv,
                          a4 * inv, a5 * inv, a6 * inv, a7 * inv};
            float skv[8] = {sk0.x, sk0.y, sk0.z, sk0.w, sk1.x, sk1.y, sk1.z, sk1.w};
            float biv[8] = {bi0.x, bi0.y, bi0.z, bi0.w, bi1.x, bi1.y, bi1.z, bi1.w};
            float bkv[8] = {bk0.x, bk0.y, bk0.z, bk0.w, bk1.x, bk1.y, bk1.z, bk1.w};
            uint_t pk[4];
            #pragma unroll
            for (int k = 0; k < 8; ++k) {
                float wv = v[k] + biv[k] + bkv[k] + skv[k];
                // fast ELU: expm1f is ~30-instr libm; __expf-1 is 2-op native
                wv = wv > 0.f ? wv : (__expf(wv) - 1.f);
                if (k & 1) pk[k >> 1] |= ((uint_t)f2bf(wv)) << 16;
                else       pk[k >> 1] = (uint_t)f2bf(wv);
            }
            uint4 o4 = make_uint4(pk[0], pk[1], pk[2], pk[3]);
            reinterpret_cast<uint4*>(outp)[(size_t)node * 16 + g] = o4;
        }
    } else {
        // per-head weighted means, then sum over heads (lanes g, g^4, g^8, g^12)
        float v[8] = {a0 * inv, a1 * inv, a2 * inv, a3 * inv,
                      a4 * inv, a5 * inv, a6 * inv, a7 * inv};
        #pragma unroll
        for (int o = 4; o <= 8; o <<= 1)
            #pragma unroll
            for (int k = 0; k < 8; ++k) v[k] += __shfl_xor(v[k], o, 64);
        if (t < 4) {
            int cb = t * 8;
            float4 bi0 = *reinterpret_cast<const float4*>(bias + cb);
            float4 bi1 = *reinterpret_cast<const float4*>(bias + cb + 4);
            float4 bk0 = *reinterpret_cast<const float4*>(biasSk + cb);
            float4 bk1 = *reinterpret_cast<const float4*>(biasSk + cb + 4);
            float4 sk0 = *reinterpret_cast<const float4*>(hsk + (size_t)node * 32 + cb);
            float4 sk1 = *reinterpret_cast<const float4*>(hsk + (size_t)node * 32 + cb + 4);
            float biv[8] = {bi0.x, bi0.y, bi0.z, bi0.w, bi1.x, bi1.y, bi1.z, bi1.w};
            float bkv[8] = {bk0.x, bk0.y, bk0.z, bk0.w, bk1.x, bk1.y, bk1.z, bk1.w};
            float skv[8] = {sk0.x, sk0.y, sk0.z, sk0.w, sk1.x, sk1.y, sk1.z, sk1.w};
            float ss = 0.f;
            #pragma unroll
            for (int k = 0; k < 8; ++k) {
                v[k] = v[k] * 0.25f + biv[k] + bkv[k] + skv[k];
                ss += v[k] * v[k];
            }
            ss += __shfl_xor(ss, 1, 64);
            ss += __shfl_xor(ss, 2, 64);
            float r = 1.f / fmaxf(sqrtf(ss), 1e-12f);
            float* out = reinterpret_cast<float*>(outp);
            float4 w0 = make_float4(v[0] * r, v[1] * r, v[2] * r, v[3] * r);
            float4 w1 = make_float4(v[4] * r, v[5] * r, v[6] * r, v[7] * r);
            *reinterpret_cast<float4*>(out + (size_t)node * 32 + cb) = w0;
            *reinterpret_cast<float4*>(out + (size_t)node * 32 + cb + 4) = w1;
        }
    }
}

// ---------------------------------------------------------------------------
// launch
// ---------------------------------------------------------------------------
extern "C" void kernel_launch(void* const* d_in, const int* in_sizes, int n_in,
                              void* d_out, int out_size, void* d_ws, size_t ws_size,
                              hipStream_t stream) {
    const float* x   = (const float*)d_in[0];
    const int*   ei  = (const int*)d_in[1];
    const float* W0  = (const float*)d_in[2];
    const float* aS0 = (const float*)d_in[3];
    const float* aD0 = (const float*)d_in[4];
    const float* b0  = (const float*)d_in[5];
    const float* Ws0 = (const float*)d_in[6];
    const float* bs0 = (const float*)d_in[7];
    const float* W1  = (const float*)d_in[8];
    const float* aS1 = (const float*)d_in[9];
    const float* aD1 = (const float*)d_in[10];
    const float* b1  = (const float*)d_in[11];
    const float* Ws1 = (const float*)d_in[12];
    const float* bs1 = (const float*)d_in[13];
    const float* W2  = (const float*)d_in[14];
    const float* aS2 = (const float*)d_in[15];
    const float* aD2 = (const float*)d_in[16];
    const float* b2  = (const float*)d_in[17];
    const float* Ws2 = (const float*)d_in[18];
    const float* bs2 = (const float*)d_in[19];
    float* out = (float*)d_out;

    char* p = (char*)d_ws;
    auto alloc = [&](size_t bytes) -> char* {
        char* q = p;
        p += (bytes + 255) & ~(size_t)255;
        return q;
    };
    int*      cnt   = (int*)alloc((size_t)NN * 4);
    int*      off   = (int*)alloc((size_t)(NN + 1) * 4);
    int*      csr   = (int*)alloc((size_t)NE * 4);
    int*      bsum  = (int*)alloc((size_t)NB * 4);
    int*      bpre  = (int*)alloc((size_t)NB * 4);
    ushort_t* hwB   = (ushort_t*)alloc((size_t)NN * 128 * 2);
    ushort_t* hbufB = (ushort_t*)alloc((size_t)NN * 128 * 2);
    float*    hsk   = (float*)alloc((size_t)NN * 128 * 4);
    float*    alS   = (float*)alloc((size_t)NN * 4 * 4);
    float*    alD   = (float*)alloc((size_t)NN * 4 * 4);
    ushort_t* Wt0   = (ushort_t*)alloc((size_t)128 * 128 * 2);
    ushort_t* Wts0  = (ushort_t*)alloc((size_t)128 * 128 * 2);
    ushort_t* Wt1   = (ushort_t*)alloc((size_t)128 * 128 * 2);
    ushort_t* Wts1  = (ushort_t*)alloc((size_t)128 * 128 * 2);
    ushort_t* Wt2   = (ushort_t*)alloc((size_t)128 * 128 * 2);
    ushort_t* Wts2  = (ushort_t*)alloc((size_t)32 * 128 * 2);

    const int EB = (NE + 255) / 256;
    const dim3 gg((NN + 127) / 128, 2);   // (391, 2)
    const int AGGB = NN / 4;

    // weight conversions + cnt zeroing (one kernel)
    wcvt_all<<<336, 256, 0, stream>>>(W0, Ws0, W1, Ws1, W2, Ws2,
                                      Wt0, Wts0, Wt1, Wts1, Wt2, Wts2, cnt);

    // CSR build
    count_kernel<<<EB, 256, 0, stream>>>(ei, cnt, NE);
    psum_kernel<<<NB, 256, 0, stream>>>(cnt, bsum);
    bscan_kernel<<<1, 256, 0, stream>>>(bsum, bpre);
    scan3_kernel<<<NB, 256, 0, stream>>>(cnt, bpre, off);
    fill_kernel<<<EB, 256, 0, stream>>>(ei, off, cnt, csr, NE);

    // ---- layer 0 (A = x fp32, converted inline)
    gemm_fused<1><<<gg, 256, 0, stream>>>(x, Wt0, hwB, Wts0, hsk,
                                          aS0, aD0, alS, alD, NN, 128);
    agg_kernel<0><<<AGGB, 256, 0, stream>>>(off, csr, alS, alD, hwB, hsk, b0, bs0, hbufB);

    // ---- layer 1 (A = hbufB bf16)
    gemm_fused<0><<<gg, 256, 0, stream>>>(hbufB, Wt1, hwB, Wts1, hsk,
                                          aS1, aD1, alS, alD, NN, 128);
    agg_kernel<0><<<AGGB, 256, 0, stream>>>(off, csr, alS, alD, hwB, hsk, b1, bs1, hbufB);

    // ---- layer 2 (skip GEMM N2=32; head-mean + L2 normalize)
    gemm_fused<0><<<gg, 256, 0, stream>>>(hbufB, Wt2, hwB, Wts2, hsk,
                                          aS2, aD2, alS, alD, NN, 32);
    agg_kernel<1><<<AGGB, 256, 0, stream>>>(off, csr, alS, alD, hwB, hsk, b2, bs2, out);
}

// Round 8
// 355.611 us; speedup vs baseline: 1.9445x; 1.0973x over previous
//
#include <hip/hip_runtime.h>
#include <hip/hip_bf16.h>
#include <cstdint>
#include <cstddef>

#define NN 50000
#define NE 800000
#define NB 196   // ceil(NN/256)

typedef __attribute__((ext_vector_type(8))) short short8v;
typedef __attribute__((ext_vector_type(4))) float f32x4;
typedef unsigned short ushort_t;
typedef unsigned int uint_t;

// ---------------------------------------------------------------------------
// helpers
// ---------------------------------------------------------------------------
__device__ __forceinline__ float lrelu(float v) {
    return v > 0.f ? v : 0.2f * v;
}
__device__ __forceinline__ ushort_t f2bf(float f) {
    __hip_bfloat16 h = __float2bfloat16(f);
    return *reinterpret_cast<ushort_t*>(&h);
}
__device__ __forceinline__ float bflo(uint_t u) { return __uint_as_float(u << 16); }
__device__ __forceinline__ float bfhi(uint_t u) { return __uint_as_float(u & 0xffff0000u); }

// ---------------------------------------------------------------------------
// all weight conversions in ONE kernel: W [128][N] fp32 -> Wt bf16 [N][128]
// also zeroes cnt (folds the memset dispatch)
// ---------------------------------------------------------------------------
__global__ __launch_bounds__(256) void wcvt_all(
    const float* __restrict__ W0, const float* __restrict__ Ws0,
    const float* __restrict__ W1, const float* __restrict__ Ws1,
    const float* __restrict__ W2, const float* __restrict__ Ws2,
    ushort_t* __restrict__ T0, ushort_t* __restrict__ Ts0,
    ushort_t* __restrict__ T1, ushort_t* __restrict__ Ts1,
    ushort_t* __restrict__ T2, ushort_t* __restrict__ Ts2,
    int* __restrict__ cnt) {
    int idx = blockIdx.x * 256 + threadIdx.x;
    if (idx < NN) cnt[idx] = 0;
    if (idx < 81920) {
        int m = idx >> 14;          // which 128x128 matrix
        int i = idx & 16383;
        const float* src; ushort_t* dst;
        switch (m) {
            case 0: src = W0;  dst = T0;  break;
            case 1: src = Ws0; dst = Ts0; break;
            case 2: src = W1;  dst = T1;  break;
            case 3: src = Ws1; dst = Ts1; break;
            default: src = W2; dst = T2;  break;
        }
        int k = i >> 7, n = i & 127;
        dst[n * 128 + k] = f2bf(src[i]);
    } else {
        int i = idx - 81920;        // 4096 elems of Ws2 [128][32]
        int k = i >> 5, n = i & 31;
        Ts2[n * 128 + k] = f2bf(Ws2[i]);
    }
}

// ---------------------------------------------------------------------------
// CSR build: count(+rank) -> 3-kernel parallel scan -> atomic-free fill
// ---------------------------------------------------------------------------
__global__ void count_rank_kernel(const int* __restrict__ ei, int* __restrict__ cnt,
                                  int* __restrict__ rank, int E) {
    int e = blockIdx.x * blockDim.x + threadIdx.x;
    if (e < E) rank[e] = atomicAdd(&cnt[ei[E + e]], 1);
}

__global__ __launch_bounds__(256) void psum_kernel(const int* __restrict__ cnt,
                                                   int* __restrict__ bsum) {
    int i = blockIdx.x * 256 + threadIdx.x;
    int v = (i < NN) ? cnt[i] : 0;
    #pragma unroll
    for (int o = 1; o < 64; o <<= 1) v += __shfl_xor(v, o, 64);
    __shared__ int ws[4];
    if ((threadIdx.x & 63) == 0) ws[threadIdx.x >> 6] = v;
    __syncthreads();
    if (threadIdx.x == 0) bsum[blockIdx.x] = ws[0] + ws[1] + ws[2] + ws[3];
}

__global__ __launch_bounds__(256) void bscan_kernel(const int* __restrict__ bsum,
                                                    int* __restrict__ bpre) {
    int t = threadIdx.x;
    int lane = t & 63, w = t >> 6;
    int v = (t < NB) ? bsum[t] : 0;
    int x = v;
    #pragma unroll
    for (int o = 1; o < 64; o <<= 1) {
        int y = __shfl_up(x, o, 64);
        if (lane >= o) x += y;
    }
    __shared__ int ws[4];
    if (lane == 63) ws[w] = x;
    __syncthreads();
    if (t == 0) {
        int s = 0;
        #pragma unroll
        for (int q = 0; q < 4; ++q) { int tmp = ws[q]; ws[q] = s; s += tmp; }
    }
    __syncthreads();
    if (t < NB) bpre[t] = (x - v) + ws[w];
}

__global__ __launch_bounds__(256) void scan3_kernel(const int* __restrict__ cnt,
                                                    const int* __restrict__ bpre,
                                                    int* __restrict__ off) {
    int b = blockIdx.x, t = threadIdx.x;
    int i = b * 256 + t;
    int lane = t & 63, w = t >> 6;
    int v = (i < NN) ? cnt[i] : 0;
    int x = v;
    #pragma unroll
    for (int o = 1; o < 64; o <<= 1) {
        int y = __shfl_up(x, o, 64);
        if (lane >= o) x += y;
    }
    __shared__ int ws[4];
    if (lane == 63) ws[w] = x;
    __syncthreads();
    if (t == 0) {
        int s = 0;
        #pragma unroll
        for (int q = 0; q < 4; ++q) { int tmp = ws[q]; ws[q] = s; s += tmp; }
    }
    __syncthreads();
    int incl = x + ws[w];
    if (i < NN) off[i + 1] = bpre[b] + incl;
    if (i == 0) off[0] = 0;
}

// atomic-free fill: rank precomputed in count pass; 2 edges/thread for ILP
__global__ void fill2_kernel(const int* __restrict__ ei, const int* __restrict__ rank,
                             const int* __restrict__ off, int* __restrict__ csr, int E) {
    int e = (blockIdx.x * blockDim.x + threadIdx.x) * 2;
    if (e + 1 < E) {
        int2 s2 = *reinterpret_cast<const int2*>(ei + e);
        int2 d2 = *reinterpret_cast<const int2*>(ei + E + e);
        int2 r2 = *reinterpret_cast<const int2*>(rank + e);
        csr[off[d2.x] + r2.x] = s2.x;
        csr[off[d2.y] + r2.y] = s2.y;
    } else if (e < E) {
        csr[off[ei[E + e]] + rank[e]] = ei[e];
    }
}

// ---------------------------------------------------------------------------
// LDS-staged MFMA GEMM + fused attention-logit epilogue. K=128 fixed.
// A: fp32 [M][128] (AFP32=1) or bf16 [M][128] (AFP32=0).
// y=0: C1 = A@B1^T -> bf16 [M][128], plus alS/alD = (A@B1)·aS/aD per head.
// y=1: C2 = A@B2^T -> fp32 [M][N2] (N2 = 128 or 32).
// LDS XOR swizzle bits 4..6 by row: stride-256B frag ds_read_b128 2-way (free).
// ---------------------------------------------------------------------------
template <int AFP32>
__global__ __launch_bounds__(256) void gemm_fused(const void* __restrict__ Ap,
                                                  const ushort_t* __restrict__ Bt1,
                                                  ushort_t* __restrict__ C1,
                                                  const ushort_t* __restrict__ Bt2,
                                                  float* __restrict__ C2,
                                                  const float* __restrict__ aS,
                                                  const float* __restrict__ aD,
                                                  float* __restrict__ alS,
                                                  float* __restrict__ alD,
                                                  int M, int N2) {
    __shared__ ushort_t As[128 * 128];   // 32KB swizzled
    __shared__ ushort_t Bs[128 * 128];   // 32KB swizzled
    const int tid = threadIdx.x;
    const int wave = tid >> 6;
    const int lane = tid & 63;
    const int l15 = lane & 15;
    const int kg = lane >> 4;            // 0..3
    const bool second = (blockIdx.y == 1);
    const int m0 = blockIdx.x * 128;
    const int Ncols = second ? N2 : 128;

    // ---- stage A (coalesced, swizzled write)
    if (AFP32) {
        const float* A = (const float*)Ap;
        const int c = tid & 31;          // 8B dest chunk / 16B src chunk
        #pragma unroll
        for (int q = 0; q < 16; ++q) {
            int row = (tid >> 5) + q * 8;
            int sr = m0 + row; sr = sr < M ? sr : M - 1;
            float4 v = *reinterpret_cast<const float4*>(A + (size_t)sr * 128 + c * 4);
            uint_t u0 = (uint_t)f2bf(v.x) | ((uint_t)f2bf(v.y) << 16);
            uint_t u1 = (uint_t)f2bf(v.z) | ((uint_t)f2bf(v.w) << 16);
            int bo = row * 256 + ((c * 8) ^ ((row & 7) << 4));
            *reinterpret_cast<uint2*>(reinterpret_cast<char*>(As) + bo) = make_uint2(u0, u1);
        }
    } else {
        const ushort_t* A = (const ushort_t*)Ap;
        const int c = tid & 15;          // 16B chunk
        #pragma unroll
        for (int q = 0; q < 8; ++q) {
            int row = (tid >> 4) + q * 16;
            int sr = m0 + row; sr = sr < M ? sr : M - 1;
            uint4 v = *reinterpret_cast<const uint4*>(A + (size_t)sr * 128 + c * 8);
            int bo = row * 256 + ((c * 16) ^ ((row & 7) << 4));
            *reinterpret_cast<uint4*>(reinterpret_cast<char*>(As) + bo) = v;
        }
    }
    // ---- stage B (rows of Bt = output cols)
    {
        const ushort_t* Bt = second ? Bt2 : Bt1;
        const int c = tid & 15;
        for (int row = tid >> 4; row < Ncols; row += 16) {
            uint4 v = *reinterpret_cast<const uint4*>(Bt + (size_t)row * 128 + c * 8);
            int bo = row * 256 + ((c * 16) ^ ((row & 7) << 4));
            *reinterpret_cast<uint4*>(reinterpret_cast<char*>(Bs) + bo) = v;
        }
    }
    __syncthreads();

    const int r0 = (wave & 1) * 64;      // tile-local row base for this wave
    const int c0 = (wave >> 1) * 64;     // col base
    if (c0 >= Ncols) return;
    const int nF = (Ncols - c0) >= 64 ? 4 : ((Ncols - c0) >> 4);

    f32x4 acc[4][4];
    #pragma unroll
    for (int i = 0; i < 4; ++i)
        #pragma unroll
        for (int j = 0; j < 4; ++j) acc[i][j] = (f32x4){0.f, 0.f, 0.f, 0.f};

    #pragma unroll
    for (int ks = 0; ks < 4; ++ks) {
        const int kb = kg * 16 + ks * 64;   // frag k byte offset
        short8v a[4], b[4];
        #pragma unroll
        for (int fm = 0; fm < 4; ++fm) {
            int row = r0 + fm * 16 + l15;
            int bo = row * 256 + (kb ^ ((row & 7) << 4));
            a[fm] = *reinterpret_cast<const short8v*>(reinterpret_cast<const char*>(As) + bo);
        }
        #pragma unroll
        for (int fn = 0; fn < 4; ++fn) {
            if (fn < nF) {
                int row = c0 + fn * 16 + l15;
                int bo = row * 256 + (kb ^ ((row & 7) << 4));
                b[fn] = *reinterpret_cast<const short8v*>(reinterpret_cast<const char*>(Bs) + bo);
            }
        }
        #pragma unroll
        for (int fm = 0; fm < 4; ++fm)
            #pragma unroll
            for (int fn = 0; fn < 4; ++fn)
                if (fn < nF)
                    acc[fm][fn] = __builtin_amdgcn_mfma_f32_16x16x32_bf16(
                        a[fm], b[fn], acc[fm][fn], 0, 0, 0);
    }

    // ---- C write.  C/D frag: col = l15, row = kg*4 + reg  [m89/m91]
    #pragma unroll
    for (int fm = 0; fm < 4; ++fm) {
        #pragma unroll
        for (int r = 0; r < 4; ++r) {
            int row = m0 + r0 + fm * 16 + kg * 4 + r;
            if (row < M) {
                #pragma unroll
                for (int fn = 0; fn < 4; ++fn) {
                    if (fn < nF) {
                        int col = c0 + fn * 16 + l15;
                        float v = acc[fm][fn][r];
                        if (second) C2[(size_t)row * Ncols + col] = v;
                        else        C1[(size_t)row * 128 + col] = f2bf(v);
                    }
                }
            }
        }
    }

    // ---- fused attention-logit epilogue (y=0 only): alS/alD from fp32 acc
    if (!second) {
        float aSv[4], aDv[4];
        #pragma unroll
        for (int fn = 0; fn < 4; ++fn) {
            aSv[fn] = aS[c0 + fn * 16 + l15];
            aDv[fn] = aD[c0 + fn * 16 + l15];
        }
        const int hb = c0 >> 5;          // head base: 0 or 2
        #pragma unroll
        for (int fm = 0; fm < 4; ++fm) {
            #pragma unroll
            for (int r = 0; r < 4; ++r) {
                float s0 = acc[fm][0][r] * aSv[0] + acc[fm][1][r] * aSv[1];
                float s1 = acc[fm][2][r] * aSv[2] + acc[fm][3][r] * aSv[3];
                float d0 = acc[fm][0][r] * aDv[0] + acc[fm][1][r] * aDv[1];
                float d1 = acc[fm][2][r] * aDv[2] + acc[fm][3][r] * aDv[3];
                #pragma unroll
                for (int o = 1; o < 16; o <<= 1) {
                    s0 += __shfl_xor(s0, o, 64);
                    s1 += __shfl_xor(s1, o, 64);
                    d0 += __shfl_xor(d0, o, 64);
                    d1 += __shfl_xor(d1, o, 64);
                }
                if (l15 == 0) {
                    int row = m0 + r0 + fm * 16 + kg * 4 + r;
                    if (row < M) {
                        *reinterpret_cast<float2*>(alS + (size_t)row * 4 + hb) = make_float2(s0, s1);
                        *reinterpret_cast<float2*>(alD + (size_t)row * 4 + hb) = make_float2(d0, d1);
                    }
                }
            }
        }
    }
}

// ---------------------------------------------------------------------------
// softmax + aggregation — chunk-preload CSR + LDS-parked softmax numerators.
// One wave per node (4 nodes / 256-thr block).  Inner loop: 4 edges/iter,
// source ids via __shfl, numerators via LDS broadcast, ONE VMEM gather.
// FINAL=0: out bf16 [N][128] (+bias+skip fp32, fast ELU).
// FINAL=1: head-mean, +skip, L2-normalize, out fp32 [N][32].
// ---------------------------------------------------------------------------
template <int FINAL>
__global__ __launch_bounds__(256) void agg_kernel(const int* __restrict__ off,
                                                  const int* __restrict__ csr,
                                                  const float* __restrict__ alS,
                                                  const float* __restrict__ alD,
                                                  const ushort_t* __restrict__ hwB,
                                                  const float* __restrict__ hsk,
                                                  const float* __restrict__ bias,
                                                  const float* __restrict__ biasSk,
                                                  void* __restrict__ outp) {
    __shared__ float ex_lds[4][64][4];       // 4KB
    const int w = threadIdx.x >> 6;
    const int node = blockIdx.x * 4 + w;
    const int t = threadIdx.x & 63;
    const int g = t & 15;                    // col group (16B of hw row)
    const int h = g >> 2;                    // head
    const int eo = t >> 4;                   // edge slot
    const int start = off[node];
    const int deg = off[node + 1] - start;
    const float4 ad4 = *reinterpret_cast<const float4*>(alD + (size_t)node * 4);
    const uint4* __restrict__ hw16 = reinterpret_cast<const uint4*>(hwB);

    float a0 = 0.f, a1 = 0.f, a2 = 0.f, a3 = 0.f;
    float a4 = 0.f, a5 = 0.f, a6 = 0.f, a7 = 0.f;
    float sA = 0.f;

    for (int cb = 0; cb < deg; cb += 64) {
        const int ce = min(64, deg - cb);
        // chunk preload + softmax numerators
        const int li = t < ce ? t : ce - 1;
        const int sv = csr[start + cb + li];
        {
            float4 al4 = *reinterpret_cast<const float4*>(alS + (size_t)sv * 4);
            bool lv = t < ce;
            float e0 = lv ? __expf(lrelu(al4.x + ad4.x)) : 0.f;
            float e1 = lv ? __expf(lrelu(al4.y + ad4.y)) : 0.f;
            float e2 = lv ? __expf(lrelu(al4.z + ad4.z)) : 0.f;
            float e3 = lv ? __expf(lrelu(al4.w + ad4.w)) : 0.f;
            *reinterpret_cast<float4*>(&ex_lds[w][t][0]) = make_float4(e0, e1, e2, e3);
        }
        // wave-private LDS: compiler inserts lgkmcnt wait; no barrier needed
        for (int jr = 0; jr < ce; jr += 4) {
            int ej = jr + eo;
            int ejc = ej < ce ? ej : 0;
            int s = __shfl(sv, ejc, 64);
            float ex = ex_lds[w][ejc][h];
            ex = (ej < ce) ? ex : 0.f;
            uint4 u = hw16[(size_t)s * 16 + g];
            sA += ex;
            a0 += ex * bflo(u.x); a1 += ex * bfhi(u.x);
            a2 += ex * bflo(u.y); a3 += ex * bfhi(u.y);
            a4 += ex * bflo(u.z); a5 += ex * bfhi(u.z);
            a6 += ex * bflo(u.w); a7 += ex * bfhi(u.w);
        }
    }

    // combine the 4 edge slots (lanes t, t^16, t^32, t^48)
    #pragma unroll
    for (int o = 16; o <= 32; o <<= 1) {
        sA += __shfl_xor(sA, o, 64);
        a0 += __shfl_xor(a0, o, 64); a1 += __shfl_xor(a1, o, 64);
        a2 += __shfl_xor(a2, o, 64); a3 += __shfl_xor(a3, o, 64);
        a4 += __shfl_xor(a4, o, 64); a5 += __shfl_xor(a5, o, 64);
        a6 += __shfl_xor(a6, o, 64); a7 += __shfl_xor(a7, o, 64);
    }
    const float inv = 1.f / (sA + 1e-16f);

    if (FINAL == 0) {
        if (t < 16) {
            int cb = g * 8;
            float4 sk0 = *reinterpret_cast<const float4*>(hsk + (size_t)node * 128 + cb);
            float4 sk1 = *reinterpret_cast<const float4*>(hsk + (size_t)node * 128 + cb + 4);
            float4 bi0 = *reinterpret_cast<const float4*>(bias + cb);
            float4 bi1 = *reinterpret_cast<const float4*>(bias + cb + 4);
            float4 bk0 = *reinterpret_cast<const float4*>(biasSk + cb);
            float4 bk1 = *reinterpret_cast<const float4*>(biasSk + cb + 4);
            float v[8] = {a0 * inv, a1 * inv, a2 * inv, a3 * inv,
                          a4 * inv, a5 * inv, a6 * inv, a7 * inv};
            float skv[8] = {sk0.x, sk0.y, sk0.z, sk0.w, sk1.x, sk1.y, sk1.z, sk1.w};
            float biv[8] = {bi0.x, bi0.y, bi0.z, bi0.w, bi1.x, bi1.y, bi1.z, bi1.w};
            float bkv[8] = {bk0.x, bk0.y, bk0.z, bk0.w, bk1.x, bk1.y, bk1.z, bk1.w};
            uint_t pk[4];
            #pragma unroll
            for (int k = 0; k < 8; ++k) {
                float wv = v[k] + biv[k] + bkv[k] + skv[k];
                // fast ELU: expm1f is ~30-instr libm; __expf-1 is 2-op native
                wv = wv > 0.f ? wv : (__expf(wv) - 1.f);
                if (k & 1) pk[k >> 1] |= ((uint_t)f2bf(wv)) << 16;
                else       pk[k >> 1] = (uint_t)f2bf(wv);
            }
            uint4 o4 = make_uint4(pk[0], pk[1], pk[2], pk[3]);
            reinterpret_cast<uint4*>(outp)[(size_t)node * 16 + g] = o4;
        }
    } else {
        // per-head weighted means, then sum over heads (lanes g, g^4, g^8, g^12)
        float v[8] = {a0 * inv, a1 * inv, a2 * inv, a3 * inv,
                      a4 * inv, a5 * inv, a6 * inv, a7 * inv};
        #pragma unroll
        for (int o = 4; o <= 8; o <<= 1)
            #pragma unroll
            for (int k = 0; k < 8; ++k) v[k] += __shfl_xor(v[k], o, 64);
        if (t < 4) {
            int cb = t * 8;
            float4 bi0 = *reinterpret_cast<const float4*>(bias + cb);
            float4 bi1 = *reinterpret_cast<const float4*>(bias + cb + 4);
            float4 bk0 = *reinterpret_cast<const float4*>(biasSk + cb);
            float4 bk1 = *reinterpret_cast<const float4*>(biasSk + cb + 4);
            float4 sk0 = *reinterpret_cast<const float4*>(hsk + (size_t)node * 32 + cb);
            float4 sk1 = *reinterpret_cast<const float4*>(hsk + (size_t)node * 32 + cb + 4);
            float biv[8] = {bi0.x, bi0.y, bi0.z, bi0.w, bi1.x, bi1.y, bi1.z, bi1.w};
            float bkv[8] = {bk0.x, bk0.y, bk0.z, bk0.w, bk1.x, bk1.y, bk1.z, bk1.w};
            float skv[8] = {sk0.x, sk0.y, sk0.z, sk0.w, sk1.x, sk1.y, sk1.z, sk1.w};
            float ss = 0.f;
            #pragma unroll
            for (int k = 0; k < 8; ++k) {
                v[k] = v[k] * 0.25f + biv[k] + bkv[k] + skv[k];
                ss += v[k] * v[k];
            }
            ss += __shfl_xor(ss, 1, 64);
            ss += __shfl_xor(ss, 2, 64);
            float r = 1.f / fmaxf(sqrtf(ss), 1e-12f);
            float* out = reinterpret_cast<float*>(outp);
            float4 w0 = make_float4(v[0] * r, v[1] * r, v[2] * r, v[3] * r);
            float4 w1 = make_float4(v[4] * r, v[5] * r, v[6] * r, v[7] * r);
            *reinterpret_cast<float4*>(out + (size_t)node * 32 + cb) = w0;
            *reinterpret_cast<float4*>(out + (size_t)node * 32 + cb + 4) = w1;
        }
    }
}

// ---------------------------------------------------------------------------
// launch
// ---------------------------------------------------------------------------
extern "C" void kernel_launch(void* const* d_in, const int* in_sizes, int n_in,
                              void* d_out, int out_size, void* d_ws, size_t ws_size,
                              hipStream_t stream) {
    const float* x   = (const float*)d_in[0];
    const int*   ei  = (const int*)d_in[1];
    const float* W0  = (const float*)d_in[2];
    const float* aS0 = (const float*)d_in[3];
    const float* aD0 = (const float*)d_in[4];
    const float* b0  = (const float*)d_in[5];
    const float* Ws0 = (const float*)d_in[6];
    const float* bs0 = (const float*)d_in[7];
    const float* W1  = (const float*)d_in[8];
    const float* aS1 = (const float*)d_in[9];
    const float* aD1 = (const float*)d_in[10];
    const float* b1  = (const float*)d_in[11];
    const float* Ws1 = (const float*)d_in[12];
    const float* bs1 = (const float*)d_in[13];
    const float* W2  = (const float*)d_in[14];
    const float* aS2 = (const float*)d_in[15];
    const float* aD2 = (const float*)d_in[16];
    const float* b2  = (const float*)d_in[17];
    const float* Ws2 = (const float*)d_in[18];
    const float* bs2 = (const float*)d_in[19];
    float* out = (float*)d_out;

    char* p = (char*)d_ws;
    auto alloc = [&](size_t bytes) -> char* {
        char* q = p;
        p += (bytes + 255) & ~(size_t)255;
        return q;
    };
    int*      cnt   = (int*)alloc((size_t)NN * 4);
    int*      off   = (int*)alloc((size_t)(NN + 1) * 4);
    int*      csr   = (int*)alloc((size_t)NE * 4);
    int*      rank  = (int*)alloc((size_t)NE * 4);
    int*      bsum  = (int*)alloc((size_t)NB * 4);
    int*      bpre  = (int*)alloc((size_t)NB * 4);
    ushort_t* hwB   = (ushort_t*)alloc((size_t)NN * 128 * 2);
    ushort_t* hbufB = (ushort_t*)alloc((size_t)NN * 128 * 2);
    float*    hsk   = (float*)alloc((size_t)NN * 128 * 4);
    float*    alS   = (float*)alloc((size_t)NN * 4 * 4);
    float*    alD   = (float*)alloc((size_t)NN * 4 * 4);
    ushort_t* Wt0   = (ushort_t*)alloc((size_t)128 * 128 * 2);
    ushort_t* Wts0  = (ushort_t*)alloc((size_t)128 * 128 * 2);
    ushort_t* Wt1   = (ushort_t*)alloc((size_t)128 * 128 * 2);
    ushort_t* Wts1  = (ushort_t*)alloc((size_t)128 * 128 * 2);
    ushort_t* Wt2   = (ushort_t*)alloc((size_t)128 * 128 * 2);
    ushort_t* Wts2  = (ushort_t*)alloc((size_t)32 * 128 * 2);

    const int EB = (NE + 255) / 256;
    const dim3 gg((NN + 127) / 128, 2);   // (391, 2)
    const int AGGB = NN / 4;

    // weight conversions + cnt zeroing (one kernel)
    wcvt_all<<<336, 256, 0, stream>>>(W0, Ws0, W1, Ws1, W2, Ws2,
                                      Wt0, Wts0, Wt1, Wts1, Wt2, Wts2, cnt);

    // CSR build (rank captured in count pass; fill is atomic-free)
    count_rank_kernel<<<EB, 256, 0, stream>>>(ei, cnt, rank, NE);
    psum_kernel<<<NB, 256, 0, stream>>>(cnt, bsum);
    bscan_kernel<<<1, 256, 0, stream>>>(bsum, bpre);
    scan3_kernel<<<NB, 256, 0, stream>>>(cnt, bpre, off);
    fill2_kernel<<<(NE / 2 + 255) / 256, 256, 0, stream>>>(ei, rank, off, csr, NE);

    // ---- layer 0 (A = x fp32, converted inline)
    gemm_fused<1><<<gg, 256, 0, stream>>>(x, Wt0, hwB, Wts0, hsk,
                                          aS0, aD0, alS, alD, NN, 128);
    agg_kernel<0><<<AGGB, 256, 0, stream>>>(off, csr, alS, alD, hwB, hsk, b0, bs0, hbufB);

    // ---- layer 1 (A = hbufB bf16)
    gemm_fused<0><<<gg, 256, 0, stream>>>(hbufB, Wt1, hwB, Wts1, hsk,
                                          aS1, aD1, alS, alD, NN, 128);
    agg_kernel<0><<<AGGB, 256, 0, stream>>>(off, csr, alS, alD, hwB, hsk, b1, bs1, hbufB);

    // ---- layer 2 (skip GEMM N2=32; head-mean + L2 normalize)
    gemm_fused<0><<<gg, 256, 0, stream>>>(hbufB, Wt2, hwB, Wts2, hsk,
                                          aS2, aD2, alS, alD, NN, 32);
    agg_kernel<1><<<AGGB, 256, 0, stream>>>(off, csr, alS, alD, hwB, hsk, b2, bs2, out);
}

// Round 10
// 348.045 us; speedup vs baseline: 1.9867x; 1.0217x over previous
//
#include <hip/hip_runtime.h>
#include <hip/hip_bf16.h>
#include <cstdint>
#include <cstddef>

#define NN 50000
#define NE 800000
#define NB 196   // ceil(NN/256)

typedef __attribute__((ext_vector_type(8))) short short8v;
typedef __attribute__((ext_vector_type(4))) float f32x4;
typedef unsigned short ushort_t;
typedef unsigned int uint_t;

// ---------------------------------------------------------------------------
// helpers
// ---------------------------------------------------------------------------
__device__ __forceinline__ float lrelu(float v) {
    return v > 0.f ? v : 0.2f * v;
}
__device__ __forceinline__ ushort_t f2bf(float f) {
    __hip_bfloat16 h = __float2bfloat16(f);
    return *reinterpret_cast<ushort_t*>(&h);
}
__device__ __forceinline__ float bflo(uint_t u) { return __uint_as_float(u << 16); }
__device__ __forceinline__ float bfhi(uint_t u) { return __uint_as_float(u & 0xffff0000u); }

// ---------------------------------------------------------------------------
// all weight conversions in ONE kernel: W [128][N] fp32 -> Wt bf16 [N][128]
// also zeroes cnt (folds the memset dispatch)
// ---------------------------------------------------------------------------
__global__ __launch_bounds__(256) void wcvt_all(
    const float* __restrict__ W0, const float* __restrict__ Ws0,
    const float* __restrict__ W1, const float* __restrict__ Ws1,
    const float* __restrict__ W2, const float* __restrict__ Ws2,
    ushort_t* __restrict__ T0, ushort_t* __restrict__ Ts0,
    ushort_t* __restrict__ T1, ushort_t* __restrict__ Ts1,
    ushort_t* __restrict__ T2, ushort_t* __restrict__ Ts2,
    int* __restrict__ cnt) {
    int idx = blockIdx.x * 256 + threadIdx.x;
    if (idx < NN) cnt[idx] = 0;
    if (idx < 81920) {
        int m = idx >> 14;          // which 128x128 matrix
        int i = idx & 16383;
        const float* src; ushort_t* dst;
        switch (m) {
            case 0: src = W0;  dst = T0;  break;
            case 1: src = Ws0; dst = Ts0; break;
            case 2: src = W1;  dst = T1;  break;
            case 3: src = Ws1; dst = Ts1; break;
            default: src = W2; dst = T2;  break;
        }
        int k = i >> 7, n = i & 127;
        dst[n * 128 + k] = f2bf(src[i]);
    } else {
        int i = idx - 81920;        // 4096 elems of Ws2 [128][32]
        int k = i >> 5, n = i & 31;
        Ts2[n * 128 + k] = f2bf(Ws2[i]);
    }
}

// ---------------------------------------------------------------------------
// CSR build: count(+rank) -> 3-kernel parallel scan -> atomic-free fill
// ---------------------------------------------------------------------------
__global__ void count_rank_kernel(const int* __restrict__ ei, int* __restrict__ cnt,
                                  int* __restrict__ rank, int E) {
    int e = (blockIdx.x * blockDim.x + threadIdx.x) * 2;
    if (e + 1 < E) {
        int2 d2 = *reinterpret_cast<const int2*>(ei + E + e);
        int r0 = atomicAdd(&cnt[d2.x], 1);
        int r1 = atomicAdd(&cnt[d2.y], 1);
        *reinterpret_cast<int2*>(rank + e) = make_int2(r0, r1);
    } else if (e < E) {
        rank[e] = atomicAdd(&cnt[ei[E + e]], 1);
    }
}

__global__ __launch_bounds__(256) void psum_kernel(const int* __restrict__ cnt,
                                                   int* __restrict__ bsum) {
    int i = blockIdx.x * 256 + threadIdx.x;
    int v = (i < NN) ? cnt[i] : 0;
    #pragma unroll
    for (int o = 1; o < 64; o <<= 1) v += __shfl_xor(v, o, 64);
    __shared__ int ws[4];
    if ((threadIdx.x & 63) == 0) ws[threadIdx.x >> 6] = v;
    __syncthreads();
    if (threadIdx.x == 0) bsum[blockIdx.x] = ws[0] + ws[1] + ws[2] + ws[3];
}

__global__ __launch_bounds__(256) void bscan_kernel(const int* __restrict__ bsum,
                                                    int* __restrict__ bpre) {
    int t = threadIdx.x;
    int lane = t & 63, w = t >> 6;
    int v = (t < NB) ? bsum[t] : 0;
    int x = v;
    #pragma unroll
    for (int o = 1; o < 64; o <<= 1) {
        int y = __shfl_up(x, o, 64);
        if (lane >= o) x += y;
    }
    __shared__ int ws[4];
    if (lane == 63) ws[w] = x;
    __syncthreads();
    if (t == 0) {
        int s = 0;
        #pragma unroll
        for (int q = 0; q < 4; ++q) { int tmp = ws[q]; ws[q] = s; s += tmp; }
    }
    __syncthreads();
    if (t < NB) bpre[t] = (x - v) + ws[w];
}

__global__ __launch_bounds__(256) void scan3_kernel(const int* __restrict__ cnt,
                                                    const int* __restrict__ bpre,
                                                    int* __restrict__ off) {
    int b = blockIdx.x, t = threadIdx.x;
    int i = b * 256 + t;
    int lane = t & 63, w = t >> 6;
    int v = (i < NN) ? cnt[i] : 0;
    int x = v;
    #pragma unroll
    for (int o = 1; o < 64; o <<= 1) {
        int y = __shfl_up(x, o, 64);
        if (lane >= o) x += y;
    }
    __shared__ int ws[4];
    if (lane == 63) ws[w] = x;
    __syncthreads();
    if (t == 0) {
        int s = 0;
        #pragma unroll
        for (int q = 0; q < 4; ++q) { int tmp = ws[q]; ws[q] = s; s += tmp; }
    }
    __syncthreads();
    int incl = x + ws[w];
    if (i < NN) off[i + 1] = bpre[b] + incl;
    if (i == 0) off[0] = 0;
}

// atomic-free fill: rank precomputed in count pass; 2 edges/thread for ILP
__global__ void fill2_kernel(const int* __restrict__ ei, const int* __restrict__ rank,
                             const int* __restrict__ off, int* __restrict__ csr, int E) {
    int e = (blockIdx.x * blockDim.x + threadIdx.x) * 2;
    if (e + 1 < E) {
        int2 s2 = *reinterpret_cast<const int2*>(ei + e);
        int2 d2 = *reinterpret_cast<const int2*>(ei + E + e);
        int2 r2 = *reinterpret_cast<const int2*>(rank + e);
        csr[off[d2.x] + r2.x] = s2.x;
        csr[off[d2.y] + r2.y] = s2.y;
    } else if (e < E) {
        csr[off[ei[E + e]] + rank[e]] = ei[e];
    }
}

// ---------------------------------------------------------------------------
// LDS-staged MFMA GEMM + fused attention-logit epilogue. K=128 fixed.
// A: fp32 [M][128] (AFP32=1) or bf16 [M][128] (AFP32=0).
// y=0: C1 = A@B1^T -> bf16 [M][128], plus alS/alD = (A@B1)·aS/aD per head.
// y=1: C2 = A@B2^T -> fp32 [M][N2] (N2 = 128 or 32).
// LDS XOR swizzle bits 4..6 by row: stride-256B frag ds_read_b128 2-way (free).
// ---------------------------------------------------------------------------
template <int AFP32>
__global__ __launch_bounds__(256) void gemm_fused(const void* __restrict__ Ap,
                                                  const ushort_t* __restrict__ Bt1,
                                                  ushort_t* __restrict__ C1,
                                                  const ushort_t* __restrict__ Bt2,
                                                  float* __restrict__ C2,
                                                  const float* __restrict__ aS,
                                                  const float* __restrict__ aD,
                                                  float* __restrict__ alS,
                                                  float* __restrict__ alD,
                                                  int M, int N2) {
    __shared__ ushort_t As[128 * 128];   // 32KB swizzled
    __shared__ ushort_t Bs[128 * 128];   // 32KB swizzled
    const int tid = threadIdx.x;
    const int wave = tid >> 6;
    const int lane = tid & 63;
    const int l15 = lane & 15;
    const int kg = lane >> 4;            // 0..3
    const bool second = (blockIdx.y == 1);
    const int m0 = blockIdx.x * 128;
    const int Ncols = second ? N2 : 128;

    // ---- stage A (coalesced, swizzled write)
    if (AFP32) {
        const float* A = (const float*)Ap;
        const int c = tid & 31;          // 8B dest chunk / 16B src chunk
        #pragma unroll
        for (int q = 0; q < 16; ++q) {
            int row = (tid >> 5) + q * 8;
            int sr = m0 + row; sr = sr < M ? sr : M - 1;
            float4 v = *reinterpret_cast<const float4*>(A + (size_t)sr * 128 + c * 4);
            uint_t u0 = (uint_t)f2bf(v.x) | ((uint_t)f2bf(v.y) << 16);
            uint_t u1 = (uint_t)f2bf(v.z) | ((uint_t)f2bf(v.w) << 16);
            int bo = row * 256 + ((c * 8) ^ ((row & 7) << 4));
            *reinterpret_cast<uint2*>(reinterpret_cast<char*>(As) + bo) = make_uint2(u0, u1);
        }
    } else {
        const ushort_t* A = (const ushort_t*)Ap;
        const int c = tid & 15;          // 16B chunk
        #pragma unroll
        for (int q = 0; q < 8; ++q) {
            int row = (tid >> 4) + q * 16;
            int sr = m0 + row; sr = sr < M ? sr : M - 1;
            uint4 v = *reinterpret_cast<const uint4*>(A + (size_t)sr * 128 + c * 8);
            int bo = row * 256 + ((c * 16) ^ ((row & 7) << 4));
            *reinterpret_cast<uint4*>(reinterpret_cast<char*>(As) + bo) = v;
        }
    }
    // ---- stage B (rows of Bt = output cols)
    {
        const ushort_t* Bt = second ? Bt2 : Bt1;
        const int c = tid & 15;
        for (int row = tid >> 4; row < Ncols; row += 16) {
            uint4 v = *reinterpret_cast<const uint4*>(Bt + (size_t)row * 128 + c * 8);
            int bo = row * 256 + ((c * 16) ^ ((row & 7) << 4));
            *reinterpret_cast<uint4*>(reinterpret_cast<char*>(Bs) + bo) = v;
        }
    }
    __syncthreads();

    const int r0 = (wave & 1) * 64;      // tile-local row base for this wave
    const int c0 = (wave >> 1) * 64;     // col base
    if (c0 >= Ncols) return;
    const int nF = (Ncols - c0) >= 64 ? 4 : ((Ncols - c0) >> 4);

    f32x4 acc[4][4];
    #pragma unroll
    for (int i = 0; i < 4; ++i)
        #pragma unroll
        for (int j = 0; j < 4; ++j) acc[i][j] = (f32x4){0.f, 0.f, 0.f, 0.f};

    #pragma unroll
    for (int ks = 0; ks < 4; ++ks) {
        const int kb = kg * 16 + ks * 64;   // frag k byte offset
        short8v a[4], b[4];
        #pragma unroll
        for (int fm = 0; fm < 4; ++fm) {
            int row = r0 + fm * 16 + l15;
            int bo = row * 256 + (kb ^ ((row & 7) << 4));
            a[fm] = *reinterpret_cast<const short8v*>(reinterpret_cast<const char*>(As) + bo);
        }
        #pragma unroll
        for (int fn = 0; fn < 4; ++fn) {
            if (fn < nF) {
                int row = c0 + fn * 16 + l15;
                int bo = row * 256 + (kb ^ ((row & 7) << 4));
                b[fn] = *reinterpret_cast<const short8v*>(reinterpret_cast<const char*>(Bs) + bo);
            }
        }
        #pragma unroll
        for (int fm = 0; fm < 4; ++fm)
            #pragma unroll
            for (int fn = 0; fn < 4; ++fn)
                if (fn < nF)
                    acc[fm][fn] = __builtin_amdgcn_mfma_f32_16x16x32_bf16(
                        a[fm], b[fn], acc[fm][fn], 0, 0, 0);
    }

    // ---- C write.  C/D frag: col = l15, row = kg*4 + reg  [m89/m91]
    #pragma unroll
    for (int fm = 0; fm < 4; ++fm) {
        #pragma unroll
        for (int r = 0; r < 4; ++r) {
            int row = m0 + r0 + fm * 16 + kg * 4 + r;
            if (row < M) {
                #pragma unroll
                for (int fn = 0; fn < 4; ++fn) {
                    if (fn < nF) {
                        int col = c0 + fn * 16 + l15;
                        float v = acc[fm][fn][r];
                        if (second) C2[(size_t)row * Ncols + col] = v;
                        else        C1[(size_t)row * 128 + col] = f2bf(v);
                    }
                }
            }
        }
    }

    // ---- fused attention-logit epilogue (y=0 only): alS/alD from fp32 acc
    if (!second) {
        float aSv[4], aDv[4];
        #pragma unroll
        for (int fn = 0; fn < 4; ++fn) {
            aSv[fn] = aS[c0 + fn * 16 + l15];
            aDv[fn] = aD[c0 + fn * 16 + l15];
        }
        const int hb = c0 >> 5;          // head base: 0 or 2
        #pragma unroll
        for (int fm = 0; fm < 4; ++fm) {
            #pragma unroll
            for (int r = 0; r < 4; ++r) {
                float s0 = acc[fm][0][r] * aSv[0] + acc[fm][1][r] * aSv[1];
                float s1 = acc[fm][2][r] * aSv[2] + acc[fm][3][r] * aSv[3];
                float d0 = acc[fm][0][r] * aDv[0] + acc[fm][1][r] * aDv[1];
                float d1 = acc[fm][2][r] * aDv[2] + acc[fm][3][r] * aDv[3];
                #pragma unroll
                for (int o = 1; o < 16; o <<= 1) {
                    s0 += __shfl_xor(s0, o, 64);
                    s1 += __shfl_xor(s1, o, 64);
                    d0 += __shfl_xor(d0, o, 64);
                    d1 += __shfl_xor(d1, o, 64);
                }
                if (l15 == 0) {
                    int row = m0 + r0 + fm * 16 + kg * 4 + r;
                    if (row < M) {
                        *reinterpret_cast<float2*>(alS + (size_t)row * 4 + hb) = make_float2(s0, s1);
                        *reinterpret_cast<float2*>(alD + (size_t)row * 4 + hb) = make_float2(d0, d1);
                    }
                }
            }
        }
    }
}

// ---------------------------------------------------------------------------
// softmax + aggregation — chunk-preload CSR + LDS-parked softmax numerators.
// One wave per node (4 nodes / 256-thr block).  Inner loop: 8 edges/iter
// (2 independent uint4 gathers per lane for 2x memory-level parallelism),
// source ids via __shfl, numerators via LDS broadcast.
// FINAL=0: out bf16 [N][128] (+bias+skip fp32, fast ELU).
// FINAL=1: head-mean, +skip, L2-normalize, out fp32 [N][32].
// ---------------------------------------------------------------------------
template <int FINAL>
__global__ __launch_bounds__(256) void agg_kernel(const int* __restrict__ off,
                                                  const int* __restrict__ csr,
                                                  const float* __restrict__ alS,
                                                  const float* __restrict__ alD,
                                                  const ushort_t* __restrict__ hwB,
                                                  const float* __restrict__ hsk,
                                                  const float* __restrict__ bias,
                                                  const float* __restrict__ biasSk,
                                                  void* __restrict__ outp) {
    __shared__ float ex_lds[4][64][4];       // 4KB
    const int w = threadIdx.x >> 6;
    const int node = blockIdx.x * 4 + w;
    const int t = threadIdx.x & 63;
    const int g = t & 15;                    // col group (16B of hw row)
    const int h = g >> 2;                    // head
    const int eo = t >> 4;                   // edge slot
    const int start = off[node];
    const int deg = off[node + 1] - start;
    const float4 ad4 = *reinterpret_cast<const float4*>(alD + (size_t)node * 4);
    const uint4* __restrict__ hw16 = reinterpret_cast<const uint4*>(hwB);

    float a0 = 0.f, a1 = 0.f, a2 = 0.f, a3 = 0.f;
    float a4 = 0.f, a5 = 0.f, a6 = 0.f, a7 = 0.f;
    float sA = 0.f;

    for (int cb = 0; cb < deg; cb += 64) {
        const int ce = min(64, deg - cb);
        // chunk preload + softmax numerators
        const int li = t < ce ? t : ce - 1;
        const int sv = csr[start + cb + li];
        {
            float4 al4 = *reinterpret_cast<const float4*>(alS + (size_t)sv * 4);
            bool lv = t < ce;
            float e0 = lv ? __expf(lrelu(al4.x + ad4.x)) : 0.f;
            float e1 = lv ? __expf(lrelu(al4.y + ad4.y)) : 0.f;
            float e2 = lv ? __expf(lrelu(al4.z + ad4.z)) : 0.f;
            float e3 = lv ? __expf(lrelu(al4.w + ad4.w)) : 0.f;
            *reinterpret_cast<float4*>(&ex_lds[w][t][0]) = make_float4(e0, e1, e2, e3);
        }
        // wave-private LDS: compiler inserts lgkmcnt wait; no barrier needed
        // 8 edges per iteration: both gathers issued before either is consumed
        for (int jr = 0; jr < ce; jr += 8) {
            int ej0 = jr + eo;
            int ej1 = jr + 4 + eo;
            int ec0 = ej0 < ce ? ej0 : 0;
            int ec1 = ej1 < ce ? ej1 : 0;
            int s0 = __shfl(sv, ec0, 64);
            int s1 = __shfl(sv, ec1, 64);
            uint4 u0 = hw16[(size_t)s0 * 16 + g];
            uint4 u1 = hw16[(size_t)s1 * 16 + g];
            float ex0 = ex_lds[w][ec0][h];
            float ex1 = ex_lds[w][ec1][h];
            ex0 = (ej0 < ce) ? ex0 : 0.f;
            ex1 = (ej1 < ce) ? ex1 : 0.f;
            sA += ex0;
            a0 += ex0 * bflo(u0.x); a1 += ex0 * bfhi(u0.x);
            a2 += ex0 * bflo(u0.y); a3 += ex0 * bfhi(u0.y);
            a4 += ex0 * bflo(u0.z); a5 += ex0 * bfhi(u0.z);
            a6 += ex0 * bflo(u0.w); a7 += ex0 * bfhi(u0.w);
            sA += ex1;
            a0 += ex1 * bflo(u1.x); a1 += ex1 * bfhi(u1.x);
            a2 += ex1 * bflo(u1.y); a3 += ex1 * bfhi(u1.y);
            a4 += ex1 * bflo(u1.z); a5 += ex1 * bfhi(u1.z);
            a6 += ex1 * bflo(u1.w); a7 += ex1 * bfhi(u1.w);
        }
    }

    // combine the 4 edge slots (lanes t, t^16, t^32, t^48)
    #pragma unroll
    for (int o = 16; o <= 32; o <<= 1) {
        sA += __shfl_xor(sA, o, 64);
        a0 += __shfl_xor(a0, o, 64); a1 += __shfl_xor(a1, o, 64);
        a2 += __shfl_xor(a2, o, 64); a3 += __shfl_xor(a3, o, 64);
        a4 += __shfl_xor(a4, o, 64); a5 += __shfl_xor(a5, o, 64);
        a6 += __shfl_xor(a6, o, 64); a7 += __shfl_xor(a7, o, 64);
    }
    const float inv = 1.f / (sA + 1e-16f);

    if (FINAL == 0) {
        if (t < 16) {
            int cb = g * 8;
            float4 sk0 = *reinterpret_cast<const float4*>(hsk + (size_t)node * 128 + cb);
            float4 sk1 = *reinterpret_cast<const float4*>(hsk + (size_t)node * 128 + cb + 4);
            float4 bi0 = *reinterpret_cast<const float4*>(bias + cb);
            float4 bi1 = *reinterpret_cast<const float4*>(bias + cb + 4);
            float4 bk0 = *reinterpret_cast<const float4*>(biasSk + cb);
            float4 bk1 = *reinterpret_cast<const float4*>(biasSk + cb + 4);
            float v[8] = {a0 * inv, a1 * inv, a2 * inv, a3 * inv,
                          a4 * inv, a5 * inv, a6 * inv, a7 * inv};
            float skv[8] = {sk0.x, sk0.y, sk0.z, sk0.w, sk1.x, sk1.y, sk1.z, sk1.w};
            float biv[8] = {bi0.x, bi0.y, bi0.z, bi0.w, bi1.x, bi1.y, bi1.z, bi1.w};
            float bkv[8] = {bk0.x, bk0.y, bk0.z, bk0.w, bk1.x, bk1.y, bk1.z, bk1.w};
            uint_t pk[4];
            #pragma unroll
            for (int k = 0; k < 8; ++k) {
                float wv = v[k] + biv[k] + bkv[k] + skv[k];
                // fast ELU: expm1f is ~30-instr libm; __expf-1 is 2-op native
                wv = wv > 0.f ? wv : (__expf(wv) - 1.f);
                if (k & 1) pk[k >> 1] |= ((uint_t)f2bf(wv)) << 16;
                else       pk[k >> 1] = (uint_t)f2bf(wv);
            }
            uint4 o4 = make_uint4(pk[0], pk[1], pk[2], pk[3]);
            reinterpret_cast<uint4*>(outp)[(size_t)node * 16 + g] = o4;
        }
    } else {
        // per-head weighted means, then sum over heads (lanes g, g^4, g^8, g^12)
        float v[8] = {a0 * inv, a1 * inv, a2 * inv, a3 * inv,
                      a4 * inv, a5 * inv, a6 * inv, a7 * inv};
        #pragma unroll
        for (int o = 4; o <= 8; o <<= 1)
            #pragma unroll
            for (int k = 0; k < 8; ++k) v[k] += __shfl_xor(v[k], o, 64);
        if (t < 4) {
            int cb = t * 8;
            float4 bi0 = *reinterpret_cast<const float4*>(bias + cb);
            float4 bi1 = *reinterpret_cast<const float4*>(bias + cb + 4);
            float4 bk0 = *reinterpret_cast<const float4*>(biasSk + cb);
            float4 bk1 = *reinterpret_cast<const float4*>(biasSk + cb + 4);
            float4 sk0 = *reinterpret_cast<const float4*>(hsk + (size_t)node * 32 + cb);
            float4 sk1 = *reinterpret_cast<const float4*>(hsk + (size_t)node * 32 + cb + 4);
            float biv[8] = {bi0.x, bi0.y, bi0.z, bi0.w, bi1.x, bi1.y, bi1.z, bi1.w};
            float bkv[8] = {bk0.x, bk0.y, bk0.z, bk0.w, bk1.x, bk1.y, bk1.z, bk1.w};
            float skv[8] = {sk0.x, sk0.y, sk0.z, sk0.w, sk1.x, sk1.y, sk1.z, sk1.w};
            float ss = 0.f;
            #pragma unroll
            for (int k = 0; k < 8; ++k) {
                v[k] = v[k] * 0.25f + biv[k] + bkv[k] + skv[k];
                ss += v[k] * v[k];
            }
            ss += __shfl_xor(ss, 1, 64);
            ss += __shfl_xor(ss, 2, 64);
            float r = 1.f / fmaxf(sqrtf(ss), 1e-12f);
            float* out = reinterpret_cast<float*>(outp);
            float4 w0 = make_float4(v[0] * r, v[1] * r, v[2] * r, v[3] * r);
            float4 w1 = make_float4(v[4] * r, v[5] * r, v[6] * r, v[7] * r);
            *reinterpret_cast<float4*>(out + (size_t)node * 32 + cb) = w0;
            *reinterpret_cast<float4*>(out + (size_t)node * 32 + cb + 4) = w1;
        }
    }
}

// ---------------------------------------------------------------------------
// launch
// ---------------------------------------------------------------------------
extern "C" void kernel_launch(void* const* d_in, const int* in_sizes, int n_in,
                              void* d_out, int out_size, void* d_ws, size_t ws_size,
                              hipStream_t stream) {
    const float* x   = (const float*)d_in[0];
    const int*   ei  = (const int*)d_in[1];
    const float* W0  = (const float*)d_in[2];
    const float* aS0 = (const float*)d_in[3];
    const float* aD0 = (const float*)d_in[4];
    const float* b0  = (const float*)d_in[5];
    const float* Ws0 = (const float*)d_in[6];
    const float* bs0 = (const float*)d_in[7];
    const float* W1  = (const float*)d_in[8];
    const float* aS1 = (const float*)d_in[9];
    const float* aD1 = (const float*)d_in[10];
    const float* b1  = (const float*)d_in[11];
    const float* Ws1 = (const float*)d_in[12];
    const float* bs1 = (const float*)d_in[13];
    const float* W2  = (const float*)d_in[14];
    const float* aS2 = (const float*)d_in[15];
    const float* aD2 = (const float*)d_in[16];
    const float* b2  = (const float*)d_in[17];
    const float* Ws2 = (const float*)d_in[18];
    const float* bs2 = (const float*)d_in[19];
    float* out = (float*)d_out;

    char* p = (char*)d_ws;
    auto alloc = [&](size_t bytes) -> char* {
        char* q = p;
        p += (bytes + 255) & ~(size_t)255;
        return q;
    };
    int*      cnt   = (int*)alloc((size_t)NN * 4);
    int*      off   = (int*)alloc((size_t)(NN + 1) * 4);
    int*      csr   = (int*)alloc((size_t)NE * 4);
    int*      rank  = (int*)alloc((size_t)NE * 4);
    int*      bsum  = (int*)alloc((size_t)NB * 4);
    int*      bpre  = (int*)alloc((size_t)NB * 4);
    ushort_t* hwB   = (ushort_t*)alloc((size_t)NN * 128 * 2);
    ushort_t* hbufB = (ushort_t*)alloc((size_t)NN * 128 * 2);
    float*    hsk   = (float*)alloc((size_t)NN * 128 * 4);
    float*    alS   = (float*)alloc((size_t)NN * 4 * 4);
    float*    alD   = (float*)alloc((size_t)NN * 4 * 4);
    ushort_t* Wt0   = (ushort_t*)alloc((size_t)128 * 128 * 2);
    ushort_t* Wts0  = (ushort_t*)alloc((size_t)128 * 128 * 2);
    ushort_t* Wt1   = (ushort_t*)alloc((size_t)128 * 128 * 2);
    ushort_t* Wts1  = (ushort_t*)alloc((size_t)128 * 128 * 2);
    ushort_t* Wt2   = (ushort_t*)alloc((size_t)128 * 128 * 2);
    ushort_t* Wts2  = (ushort_t*)alloc((size_t)32 * 128 * 2);

    const int EB = (NE + 255) / 256;
    const dim3 gg((NN + 127) / 128, 2);   // (391, 2)
    const int AGGB = NN / 4;

    // weight conversions + cnt zeroing (one kernel)
    wcvt_all<<<336, 256, 0, stream>>>(W0, Ws0, W1, Ws1, W2, Ws2,
                                      Wt0, Wts0, Wt1, Wts1, Wt2, Wts2, cnt);

    // CSR build (rank captured in count pass; fill is atomic-free)
    count_rank_kernel<<<(NE / 2 + 255) / 256, 256, 0, stream>>>(ei, cnt, rank, NE);
    psum_kernel<<<NB, 256, 0, stream>>>(cnt, bsum);
    bscan_kernel<<<1, 256, 0, stream>>>(bsum, bpre);
    scan3_kernel<<<NB, 256, 0, stream>>>(cnt, bpre, off);
    fill2_kernel<<<(NE / 2 + 255) / 256, 256, 0, stream>>>(ei, rank, off, csr, NE);

    // ---- layer 0 (A = x fp32, converted inline)
    gemm_fused<1><<<gg, 256, 0, stream>>>(x, Wt0, hwB, Wts0, hsk,
                                          aS0, aD0, alS, alD, NN, 128);
    agg_kernel<0><<<AGGB, 256, 0, stream>>>(off, csr, alS, alD, hwB, hsk, b0, bs0, hbufB);

    // ---- layer 1 (A = hbufB bf16)
    gemm_fused<0><<<gg, 256, 0, stream>>>(hbufB, Wt1, hwB, Wts1, hsk,
                                          aS1, aD1, alS, alD, NN, 128);
    agg_kernel<0><<<AGGB, 256, 0, stream>>>(off, csr, alS, alD, hwB, hsk, b1, bs1, hbufB);

    // ---- layer 2 (skip GEMM N2=32; head-mean + L2 normalize)
    gemm_fused<0><<<gg, 256, 0, stream>>>(hbufB, Wt2, hwB, Wts2, hsk,
                                          aS2, aD2, alS, alD, NN, 32);
    agg_kernel<1><<<AGGB, 256, 0, stream>>>(off, csr, alS, alD, hwB, hsk, b2, bs2, out);
}